// Round 5
// baseline (343.025 us; speedup 1.0000x reference)
//
#include <hip/hip_runtime.h>
#include <math.h>

// Problem constants: B=8, N=2048, DIM=64, H=8
#define BB 8
#define NN 2048
#define DD 64
#define HH 8
#define BH (BB*HH)       // 64
#define HD (HH*DD)       // 512
#define NROWS (BB*NN)    // 16384
#define QKV_COLS (3*HD)  // 1536

typedef __bf16 bf16_8 __attribute__((ext_vector_type(8)));
typedef float  f32_16 __attribute__((ext_vector_type(16)));
typedef float  f32_4  __attribute__((ext_vector_type(4)));
typedef int    i32_2  __attribute__((ext_vector_type(2)));

__device__ __forceinline__ unsigned pack_bf16(float a, float b) {
  union { __bf16 h[2]; unsigned u; } t;
  t.h[0] = (__bf16)a; t.h[1] = (__bf16)b;
  return t.u;
}

__device__ __forceinline__ float fast_exp2(float x) {
#if __has_builtin(__builtin_amdgcn_exp2f)
  return __builtin_amdgcn_exp2f(x);      // raw v_exp_f32
#else
  return __expf(x * 0.69314718056f);
#endif
}

// ---------------------------------------------------------------------------
// Kernel 0: weight prep.
//   Wqkv[64][1536] fp32 -> Wtq[1536][64] bf16, Q cols pre-scaled by
//     0.125*log2(e) (attention uses exp2 directly).
//   Wout[512][64] fp32 -> Wob: per-head MFMA B-fragment layout.
//     Wob[((h*8 + t*4 + s)*64 + lane)*8 + j] = Wout[h*64 + s*16 + (lane>>5)*8 + j]
//                                                  [t*32 + (lane&31)]
//     so the attn epilogue loads each B-frag as one coalesced b128.
// ---------------------------------------------------------------------------
__global__ __launch_bounds__(256) void wtrans_kernel(
    const float* __restrict__ Wqkv, const float* __restrict__ Wout,
    __bf16* __restrict__ Wtq, __bf16* __restrict__ Wob) {
  int idx = blockIdx.x * 256 + threadIdx.x;
  if (idx < 64 * QKV_COLS) {
    int col = idx % QKV_COLS;
    int k   = idx / QKV_COLS;
    float v = Wqkv[idx];
    if (col < HD) v *= 0.125f * 1.44269504088896f;   // 1/sqrt(64) * log2(e)
    Wtq[col * 64 + k] = (__bf16)v;
  } else {
    int j2 = idx - 64 * QKV_COLS;       // 0..32767 over Wout [512][64]
    int dfull = j2 >> 6, co = j2 & 63;
    int h  = dfull >> 6, dl = dfull & 63;
    int s  = dl >> 4, rem = dl & 15;
    int lh = rem >> 3, jj = rem & 7;
    int t  = co >> 5, lc = co & 31;
    int lane = lh * 32 + lc;
    Wob[(((h * 8 + t * 4 + s) * 64) + lane) * 8 + jj] = (__bf16)Wout[j2];
  }
}

// ---------------------------------------------------------------------------
// Kernel 1: QKV projection via MFMA, V written TRANSPOSED (fused vtrans).
// Q/K -> [bh][n][64] bf16; V -> Vt [bh][64][n] bf16 via per-wave LDS
// transpose (no barrier: wave-private region, DS in-order).
// ---------------------------------------------------------------------------
__global__ __launch_bounds__(256) void qkv_kernel(
    const float* __restrict__ x, const __bf16* __restrict__ Wtq,
    __bf16* __restrict__ Q, __bf16* __restrict__ K, __bf16* __restrict__ Vt) {
  __shared__ __bf16 T[4][64][34];       // per-wave transpose tile (+2 pad)
  const int lane = threadIdx.x & 63;
  const int wave = threadIdx.x >> 6;
  const int l31  = lane & 31, lhi = lane >> 5;
  const int cg   = blockIdx.x;                    // 0..23 (64-col group)
  const int row0 = blockIdx.y * 128 + wave * 32;

  // A-frags: A[m=l31][k = s*16 + lhi*8 + j], fp32 -> bf16
  const float* xr = x + (size_t)(row0 + l31) * 64 + lhi * 8;
  bf16_8 af[4];
#pragma unroll
  for (int s = 0; s < 4; s++) {
    f32_4 a0 = *(const f32_4*)(xr + s * 16);
    f32_4 a1 = *(const f32_4*)(xr + s * 16 + 4);
#pragma unroll
    for (int j = 0; j < 4; j++) { af[s][j] = (__bf16)a0[j]; af[s][4 + j] = (__bf16)a1[j]; }
  }

  f32_16 C0, C1;
#pragma unroll
  for (int i = 0; i < 16; i++) { C0[i] = 0.f; C1[i] = 0.f; }

  const __bf16* wb = Wtq + (size_t)cg * 64 * 64 + lhi * 8;
#pragma unroll
  for (int s = 0; s < 4; s++) {
    bf16_8 b0 = *(const bf16_8*)(wb + (size_t)l31 * 64 + s * 16);
    bf16_8 b1 = *(const bf16_8*)(wb + (size_t)(32 + l31) * 64 + s * 16);
    C0 = __builtin_amdgcn_mfma_f32_32x32x16_bf16(af[s], b0, C0, 0, 0, 0);
    C1 = __builtin_amdgcn_mfma_f32_32x32x16_bf16(af[s], b1, C1, 0, 0, 0);
  }

  const int col0  = cg * 64;
  const int which = col0 >> 9;          // 0=Q 1=K 2=V
  const int h     = (col0 >> 6) & 7;
  const int b     = row0 >> 11;
  const int n0l   = row0 & 2047;

  if (which < 2) {
    __bf16* dst = (which == 0) ? Q : K;
#pragma unroll
    for (int r = 0; r < 16; r++) {
      int nl = (r & 3) + 8 * (r >> 2) + 4 * lhi;
      size_t base = (((size_t)(b * HH + h) * NN) + n0l + nl) * DD;
      dst[base + l31]      = (__bf16)C0[r];
      dst[base + 32 + l31] = (__bf16)C1[r];
    }
  } else {
    // transpose 32n x 64d -> Vt[bh][d][n]
    __bf16 (*Tw)[34] = T[wave];
#pragma unroll
    for (int r = 0; r < 16; r++) {
      int nl = (r & 3) + 8 * (r >> 2) + 4 * lhi;
      Tw[l31][nl]      = (__bf16)C0[r];
      Tw[32 + l31][nl] = (__bf16)C1[r];
    }
    __bf16* dst = Vt + (((size_t)(b * HH + h) * DD) + lane) * NN + n0l;
#pragma unroll
    for (int j = 0; j < 4; j++) {
      *(bf16_8*)(dst + j * 8) = *(const bf16_8*)(&Tw[lane][j * 8]);
    }
  }
}

// ---------------------------------------------------------------------------
// Kernel 2: BARRIER-FREE fused flash attention + output projection.
// No LDS, no __syncthreads. All K / V^T MFMA fragments are direct global
// b128 loads (L1/L2-served: tiles shared across 4 waves x 16 blocks).
//   S^T = K @ Q^T ; P^T = exp2(S^T) in-reg ; O^T += V^T @ P^T
//   epilogue: O^T (C-layout) -> A-frags via permlane32-swap (same algebra
//   as the P conversion), x Wob B-frags -> 32x64 out partial, atomicAdd.
// Bias is added by the h==0 blocks (once per output row).
// ---------------------------------------------------------------------------
__global__ __launch_bounds__(256, 3) void attn_kernel(
    const __bf16* __restrict__ Q, const __bf16* __restrict__ K,
    const __bf16* __restrict__ Vt, const __bf16* __restrict__ Wob,
    const float* __restrict__ bout, float* __restrict__ out) {
  const int tid  = threadIdx.x;
  const int wave = tid >> 6;
  const int lane = tid & 63;
  const int l31  = lane & 31;
  const int lhi  = lane >> 5;
  const int xl   = lane ^ 32;
  const int bh   = blockIdx.x >> 4;
  const int q0   = (blockIdx.x & 15) * 128 + wave * 32;

  // Q fragments (B-operand: n=query=l31, k = s*16 + lhi*8 + j)
  const __bf16* Qbase = Q + ((size_t)bh * NN + q0 + l31) * DD + lhi * 8;
  bf16_8 qf[4];
#pragma unroll
  for (int s = 0; s < 4; s++) qf[s] = *(const bf16_8*)(Qbase + s * 16);

  f32_16 O0, O1;
#pragma unroll
  for (int i = 0; i < 16; i++) { O0[i] = 0.f; O1[i] = 0.f; }
  float ls0 = 0.f, ls1 = 0.f;

  const __bf16* Kb = K  + (size_t)bh * NN * DD;
  const __bf16* Vb = Vt + (size_t)bh * DD * NN;

  for (int c = 0; c < 32; c++) {        // 64-key chunks
    // K A-frags: rows = keys c*64 + l31 (+32), cols d = s*16+lhi*8+{0..7}
    const __bf16* kf = Kb + (size_t)(c * 64 + l31) * 64 + lhi * 8;
    // V^T A-frags: rows = d = l31 (+32), cols keys = c*64 + g*16+lhi*8+{0..7}
    const __bf16* vf = Vb + (size_t)l31 * NN + c * 64 + lhi * 8;

    bf16_8 kb0[4], kb1[4], va0[4], va1[4];
#pragma unroll
    for (int s = 0; s < 4; s++) {
      kb0[s] = *(const bf16_8*)(kf + s * 16);
      kb1[s] = *(const bf16_8*)(kf + 32 * 64 + s * 16);
    }
#pragma unroll
    for (int g = 0; g < 4; g++) {
      va0[g] = *(const bf16_8*)(vf + g * 16);
      va1[g] = *(const bf16_8*)(vf + (size_t)32 * NN + g * 16);
    }

    // S^T = K @ Q^T
    f32_16 S0, S1;
#pragma unroll
    for (int i = 0; i < 16; i++) { S0[i] = 0.f; S1[i] = 0.f; }
#pragma unroll
    for (int s = 0; s < 4; s++) {
      S0 = __builtin_amdgcn_mfma_f32_32x32x16_bf16(kb0[s], qf[s], S0, 0, 0, 0);
      S1 = __builtin_amdgcn_mfma_f32_32x32x16_bf16(kb1[s], qf[s], S1, 0, 0, 0);
    }

    // P^T = exp2(S^T)  (log2(e)/8 folded into Q weights)
    unsigned pk[16];
#pragma unroll
    for (int t = 0; t < 8; t++) {
      float a = fast_exp2(S0[2 * t]), b = fast_exp2(S0[2 * t + 1]);
      float cc = fast_exp2(S1[2 * t]), d = fast_exp2(S1[2 * t + 1]);
      ls0 += a + b;
      ls1 += cc + d;
      pk[t]     = pack_bf16(a, b);
      pk[8 + t] = pack_bf16(cc, d);
    }

    // O^T += V^T @ P^T  (B-frags via lane^32 half-swap)
#pragma unroll
    for (int g = 0; g < 4; g++) {
      const int base = (g >> 1) * 8 + (g & 1) * 4;
      int a0 = (int)pk[base + 0], a1 = (int)pk[base + 1];
      int a2 = (int)pk[base + 2], a3 = (int)pk[base + 3];
      union { unsigned u[4]; bf16_8 v; } F;
#if __has_builtin(__builtin_amdgcn_permlane32_swap)
      i32_2 r02 = __builtin_amdgcn_permlane32_swap(a0, a2, false, false);
      i32_2 r13 = __builtin_amdgcn_permlane32_swap(a1, a3, false, false);
      F.u[0] = (unsigned)r02.x; F.u[2] = (unsigned)r02.y;
      F.u[1] = (unsigned)r13.x; F.u[3] = (unsigned)r13.y;
#else
      unsigned w0 = (unsigned)__shfl(a0, xl, 64);
      unsigned w1 = (unsigned)__shfl(a1, xl, 64);
      unsigned w2 = (unsigned)__shfl(a2, xl, 64);
      unsigned w3 = (unsigned)__shfl(a3, xl, 64);
      F.u[0] = lhi ? w2 : (unsigned)a0;
      F.u[1] = lhi ? w3 : (unsigned)a1;
      F.u[2] = lhi ? (unsigned)a2 : w0;
      F.u[3] = lhi ? (unsigned)a3 : w1;
#endif
      O0 = __builtin_amdgcn_mfma_f32_32x32x16_bf16(va0[g], F.v, O0, 0, 0, 0);
      O1 = __builtin_amdgcn_mfma_f32_32x32x16_bf16(va1[g], F.v, O1, 0, 0, 0);
    }
  }

  // softmax denominator: partner lane (^32) holds the other half of the keys
  float lsum = ls0 + ls1;
  lsum += __shfl_xor(lsum, 32, 64);
  const float inv = 1.f / lsum;

  // ---- fused output projection: D = O @ Wout_h, atomicAdd into out ----
  // normalize + pack O^T into the same pk-pair form as P
  unsigned ok[16];
#pragma unroll
  for (int t = 0; t < 8; t++) {
    ok[t]     = pack_bf16(O0[2 * t] * inv, O0[2 * t + 1] * inv);
    ok[8 + t] = pack_bf16(O1[2 * t] * inv, O1[2 * t + 1] * inv);
  }

  const int h = bh & 7;
  const __bf16* Wbh = Wob + (size_t)h * 8 * 64 * 8;
  f32_16 D0, D1;
#pragma unroll
  for (int i = 0; i < 16; i++) { D0[i] = 0.f; D1[i] = 0.f; }

#pragma unroll
  for (int s = 0; s < 4; s++) {        // kstep over d; A-frag = half-swap of ok
    const int base = (s >> 1) * 8 + (s & 1) * 4;
    int a0 = (int)ok[base + 0], a1 = (int)ok[base + 1];
    int a2 = (int)ok[base + 2], a3 = (int)ok[base + 3];
    union { unsigned u[4]; bf16_8 v; } F;
#if __has_builtin(__builtin_amdgcn_permlane32_swap)
    i32_2 r02 = __builtin_amdgcn_permlane32_swap(a0, a2, false, false);
    i32_2 r13 = __builtin_amdgcn_permlane32_swap(a1, a3, false, false);
    F.u[0] = (unsigned)r02.x; F.u[2] = (unsigned)r02.y;
    F.u[1] = (unsigned)r13.x; F.u[3] = (unsigned)r13.y;
#else
    unsigned w0 = (unsigned)__shfl(a0, xl, 64);
    unsigned w1 = (unsigned)__shfl(a1, xl, 64);
    unsigned w2 = (unsigned)__shfl(a2, xl, 64);
    unsigned w3 = (unsigned)__shfl(a3, xl, 64);
    F.u[0] = lhi ? w2 : (unsigned)a0;
    F.u[1] = lhi ? w3 : (unsigned)a1;
    F.u[2] = lhi ? (unsigned)a2 : w0;
    F.u[3] = lhi ? (unsigned)a3 : w1;
#endif
    bf16_8 b0 = *(const bf16_8*)(Wbh + ((size_t)(0 * 4 + s) * 64 + lane) * 8);
    bf16_8 b1 = *(const bf16_8*)(Wbh + ((size_t)(1 * 4 + s) * 64 + lane) * 8);
    D0 = __builtin_amdgcn_mfma_f32_32x32x16_bf16(F.v, b0, D0, 0, 0, 0);
    D1 = __builtin_amdgcn_mfma_f32_32x32x16_bf16(F.v, b1, D1, 0, 0, 0);
  }

  const int b = bh >> 3;
  const float bi0 = (h == 0) ? bout[l31]      : 0.f;
  const float bi1 = (h == 0) ? bout[32 + l31] : 0.f;
  float* ob = out + ((size_t)b * NN + q0) * 64;
#pragma unroll
  for (int r = 0; r < 16; r++) {
    int qr = (r & 3) + 8 * (r >> 2) + 4 * lhi;
    atomicAdd(&ob[(size_t)qr * 64 + l31],      D0[r] + bi0);
    atomicAdd(&ob[(size_t)qr * 64 + 32 + l31], D1[r] + bi1);
  }
}

// ---------------------------------------------------------------------------
extern "C" void kernel_launch(void* const* d_in, const int* in_sizes, int n_in,
                              void* d_out, int out_size, void* d_ws, size_t ws_size,
                              hipStream_t stream) {
  const float* x    = (const float*)d_in[0];
  const float* Wqkv = (const float*)d_in[1];
  const float* Wout = (const float*)d_in[2];
  const float* bout = (const float*)d_in[3];
  float* out = (float*)d_out;

  const size_t buf_elems = (size_t)BB * HH * NN * DD;  // 8388608
  __bf16* Qw  = (__bf16*)d_ws;
  __bf16* Kw  = Qw  + buf_elems;
  __bf16* Vtw = Kw  + buf_elems;
  __bf16* Wtq = Vtw + buf_elems;
  __bf16* Wob = Wtq + (size_t)QKV_COLS * 64;

  hipMemsetAsync(out, 0, (size_t)NROWS * DD * sizeof(float), stream);
  wtrans_kernel<<<512, 256, 0, stream>>>(Wqkv, Wout, Wtq, Wob);
  qkv_kernel<<<dim3(QKV_COLS / 64, NROWS / 128), 256, 0, stream>>>(x, Wtq, Qw, Kw, Vtw);
  attn_kernel<<<BH * (NN / 128), 256, 0, stream>>>(Qw, Kw, Vtw, Wob, bout, out);
}

// Round 6
// 220.414 us; speedup vs baseline: 1.5563x; 1.5563x over previous
//
#include <hip/hip_runtime.h>
#include <math.h>

// Problem constants: B=8, N=2048, DIM=64, H=8
#define BB 8
#define NN 2048
#define DD 64
#define HH 8
#define BH (BB*HH)       // 64
#define HD (HH*DD)       // 512
#define NROWS (BB*NN)    // 16384
#define QKV_COLS (3*HD)  // 1536

typedef __bf16 bf16_8 __attribute__((ext_vector_type(8)));
typedef __bf16 bf16_4 __attribute__((ext_vector_type(4)));
typedef float  f32_16 __attribute__((ext_vector_type(16)));
typedef float  f32_4  __attribute__((ext_vector_type(4)));
typedef int    i32_2  __attribute__((ext_vector_type(2)));

#define QSCALE 0.180336880111f   // 0.125 * log2(e), folded into Q

__device__ __forceinline__ unsigned pack_bf16(float a, float b) {
  union { __bf16 h[2]; unsigned u; } t;
  t.h[0] = (__bf16)a; t.h[1] = (__bf16)b;
  return t.u;
}

__device__ __forceinline__ float fast_exp2(float x) {
#if __has_builtin(__builtin_amdgcn_exp2f)
  return __builtin_amdgcn_exp2f(x);      // raw v_exp_f32
#else
  return __expf(x * 0.69314718056f);
#endif
}

// half-swap across the lane-32 boundary: C-layout row-spread -> A/B-operand
// k-spread (verified rounds 3-5)
__device__ __forceinline__ bf16_8 half_swap(unsigned a0, unsigned a1,
                                            unsigned a2, unsigned a3,
                                            int lhi, int xl) {
  union { unsigned u[4]; bf16_8 v; } F;
#if __has_builtin(__builtin_amdgcn_permlane32_swap)
  i32_2 r02 = __builtin_amdgcn_permlane32_swap((int)a0, (int)a2, false, false);
  i32_2 r13 = __builtin_amdgcn_permlane32_swap((int)a1, (int)a3, false, false);
  F.u[0] = (unsigned)r02.x; F.u[2] = (unsigned)r02.y;
  F.u[1] = (unsigned)r13.x; F.u[3] = (unsigned)r13.y;
#else
  unsigned w0 = (unsigned)__shfl((int)a0, xl, 64);
  unsigned w1 = (unsigned)__shfl((int)a1, xl, 64);
  unsigned w2 = (unsigned)__shfl((int)a2, xl, 64);
  unsigned w3 = (unsigned)__shfl((int)a3, xl, 64);
  F.u[0] = lhi ? w2 : a0;
  F.u[1] = lhi ? w3 : a1;
  F.u[2] = lhi ? a2 : w0;
  F.u[3] = lhi ? a3 : w1;
#endif
  return F.v;
}

// ---------------------------------------------------------------------------
// Kernel 1: QKV projection via MFMA, reading W_qkv fp32 directly (no weight
// prep kernel). V written TRANSPOSED via per-wave LDS tile. The extra grid
// row (blockIdx.y == NROWS/128) converts Wout -> Wob B-fragment layout:
//   Wob[((t*32 + s)*64 + lane)*8 + j] = Wout[s*16 + (lane>>5)*8 + j][t*32 + (lane&31)]
// ---------------------------------------------------------------------------
__global__ __launch_bounds__(256) void qkv_kernel(
    const float* __restrict__ x, const float* __restrict__ Wqkv,
    const float* __restrict__ Wout,
    __bf16* __restrict__ Q, __bf16* __restrict__ K, __bf16* __restrict__ Vt,
    __bf16* __restrict__ Wob) {
  __shared__ __bf16 T[4][64][34];       // per-wave transpose tile (+2 pad)

  if (blockIdx.y == (NROWS / 128)) {    // weight-prep row (24 blocks)
    int id = blockIdx.x * 256 + threadIdx.x;   // 0..6143
    for (int e = id; e < 512 * 64; e += 24 * 256) {
      int kf = e >> 6, col = e & 63;
      int s = kf >> 4, lh = (kf >> 3) & 1, j = kf & 7;
      int t = col >> 5, lc = col & 31;
      Wob[((size_t)((t * 32 + s) * 64 + lh * 32 + lc)) * 8 + j] = (__bf16)Wout[e];
    }
    return;
  }

  const int lane = threadIdx.x & 63;
  const int wave = threadIdx.x >> 6;
  const int l31  = lane & 31, lhi = lane >> 5;
  const int cg   = blockIdx.x;                    // 0..23 (64-col group)
  const int row0 = blockIdx.y * 128 + wave * 32;

  // A-frags: A[m=l31][k = s*16 + lhi*8 + j], fp32 -> bf16
  const float* xr = x + (size_t)(row0 + l31) * 64 + lhi * 8;
  bf16_8 af[4];
#pragma unroll
  for (int s = 0; s < 4; s++) {
    f32_4 a0 = *(const f32_4*)(xr + s * 16);
    f32_4 a1 = *(const f32_4*)(xr + s * 16 + 4);
#pragma unroll
    for (int j = 0; j < 4; j++) { af[s][j] = (__bf16)a0[j]; af[s][4 + j] = (__bf16)a1[j]; }
  }

  const int col0  = cg * 64;
  const int which = col0 >> 9;          // 0=Q 1=K 2=V
  const float wscl = (which == 0) ? QSCALE : 1.0f;

  f32_16 C0, C1;
#pragma unroll
  for (int i = 0; i < 16; i++) { C0[i] = 0.f; C1[i] = 0.f; }

  // B-frags read directly from fp32 Wqkv[k][1536]: lanes consecutive cols
#pragma unroll
  for (int s = 0; s < 4; s++) {
    bf16_8 b0, b1;
#pragma unroll
    for (int j = 0; j < 8; j++) {
      int k = s * 16 + lhi * 8 + j;
      b0[j] = (__bf16)(Wqkv[(size_t)k * QKV_COLS + col0 + l31]      * wscl);
      b1[j] = (__bf16)(Wqkv[(size_t)k * QKV_COLS + col0 + 32 + l31] * wscl);
    }
    C0 = __builtin_amdgcn_mfma_f32_32x32x16_bf16(af[s], b0, C0, 0, 0, 0);
    C1 = __builtin_amdgcn_mfma_f32_32x32x16_bf16(af[s], b1, C1, 0, 0, 0);
  }

  const int h   = (col0 >> 6) & 7;
  const int b   = row0 >> 11;
  const int n0l = row0 & 2047;

  if (which < 2) {
    __bf16* dst = (which == 0) ? Q : K;
#pragma unroll
    for (int r = 0; r < 16; r++) {
      int nl = (r & 3) + 8 * (r >> 2) + 4 * lhi;
      size_t base = (((size_t)(b * HH + h) * NN) + n0l + nl) * DD;
      dst[base + l31]      = (__bf16)C0[r];
      dst[base + 32 + l31] = (__bf16)C1[r];
    }
  } else {
    // transpose 32n x 64d -> Vt[bh][d][n]  (wave-private tile, no barrier)
    __bf16 (*Tw)[34] = T[wave];
#pragma unroll
    for (int r = 0; r < 16; r++) {
      int nl = (r & 3) + 8 * (r >> 2) + 4 * lhi;
      Tw[l31][nl]      = (__bf16)C0[r];
      Tw[32 + l31][nl] = (__bf16)C1[r];
    }
    __bf16* dst = Vt + (((size_t)(b * HH + h) * DD) + lane) * NN + n0l;
#pragma unroll
    for (int j = 0; j < 4; j++) {
      *(bf16_8*)(dst + j * 8) = *(const bf16_8*)(&Tw[lane][j * 8]);
    }
  }
}

// ---------------------------------------------------------------------------
// Kernel 2: flash attention, 8-wave blocks (512 thr), 256 queries/block,
// K-tile = 128 staged in LDS (shared by all 8 waves), reg-prefetch pipeline,
// S^T formulation with in-register P^T (no LDS round-trip), exp2.
// ---------------------------------------------------------------------------
__global__ __launch_bounds__(512, 4) void attn_kernel(
    const __bf16* __restrict__ Q, const __bf16* __restrict__ K,
    const __bf16* __restrict__ Vt, __bf16* __restrict__ z) {
  __shared__ __bf16 SMEM[128 * 72 + 64 * 136];   // Ks | Vs = 35840 B
  __bf16* Ks = SMEM;                    // [key][d], pitch 72
  __bf16* Vs = SMEM + 128 * 72;         // [d][key], pitch 136

  const int tid  = threadIdx.x;
  const int wave = tid >> 6;
  const int lane = tid & 63;
  const int l31  = lane & 31;
  const int lhi  = lane >> 5;
  const int xl   = lane ^ 32;
  const int bh   = blockIdx.x >> 3;                     // 0..63
  const int q0   = (blockIdx.x & 7) * 256 + wave * 32;  // 32 queries/wave

  // Q fragments (B-operand: n=query=l31, k = s*16 + lhi*8 + j)
  const __bf16* Qbase = Q + ((size_t)bh * NN + q0 + l31) * DD + lhi * 8;
  bf16_8 qf[4];
#pragma unroll
  for (int s = 0; s < 4; s++) qf[s] = *(const bf16_8*)(Qbase + s * 16);

  f32_16 O0, O1;
#pragma unroll
  for (int i = 0; i < 16; i++) { O0[i] = 0.f; O1[i] = 0.f; }
  float ls0 = 0.f, ls1 = 0.f;

  const __bf16* Kb = K  + (size_t)bh * NN * DD;
  const __bf16* Vb = Vt + (size_t)bh * DD * NN;

  // staging split across 512 threads: 2 b128 each for K and V
  const int krow = tid >> 3, kcol = (tid & 7) * 8;    // K: 128 x 64, 64 rows/pass
  const int vrow = tid >> 4, vcol = (tid & 15) * 8;   // V: 64 x 128, 32 rows/pass
  const __bf16* kgl = Kb + (size_t)krow * 64 + kcol;
  const __bf16* vgl = Vb + (size_t)vrow * NN + vcol;
  __bf16* klds = &Ks[krow * 72 + kcol];
  __bf16* vlds = &Vs[vrow * 136 + vcol];

  bf16_8 gk[2], gv[2];
#pragma unroll
  for (int i = 0; i < 2; i++) {
    gk[i] = *(const bf16_8*)(kgl + (size_t)i * 64 * 64);
    gv[i] = *(const bf16_8*)(vgl + (size_t)i * 32 * NN);
  }

  for (int kt = 0; kt < NN; kt += 128) {
    __syncthreads();
#pragma unroll
    for (int i = 0; i < 2; i++) {
      *(bf16_8*)(klds + i * 64 * 72)  = gk[i];
      *(bf16_8*)(vlds + i * 32 * 136) = gv[i];
    }
    __syncthreads();
    if (kt + 128 < NN) {                 // prefetch next tile into regs
#pragma unroll
      for (int i = 0; i < 2; i++) {
        gk[i] = *(const bf16_8*)(kgl + (size_t)(kt + 128) * 64 + (size_t)i * 64 * 64);
        gv[i] = *(const bf16_8*)(vgl + (kt + 128) + (size_t)i * 32 * NN);
      }
    }

#pragma unroll
    for (int hf = 0; hf < 2; hf++) {     // two 64-key halves of the tile
      // S^T = K @ Q^T
      f32_16 S0, S1;
#pragma unroll
      for (int i = 0; i < 16; i++) { S0[i] = 0.f; S1[i] = 0.f; }
#pragma unroll
      for (int s = 0; s < 4; s++) {
        bf16_8 kb0 = *(const bf16_8*)(&Ks[(hf * 64 + l31) * 72 + s * 16 + lhi * 8]);
        bf16_8 kb1 = *(const bf16_8*)(&Ks[(hf * 64 + 32 + l31) * 72 + s * 16 + lhi * 8]);
        S0 = __builtin_amdgcn_mfma_f32_32x32x16_bf16(kb0, qf[s], S0, 0, 0, 0);
        S1 = __builtin_amdgcn_mfma_f32_32x32x16_bf16(kb1, qf[s], S1, 0, 0, 0);
      }

      // P^T = exp2(S^T)  (log2(e)/8 folded into Q)
      unsigned pk[16];
#pragma unroll
      for (int t = 0; t < 8; t++) {
        float a = fast_exp2(S0[2 * t]), b = fast_exp2(S0[2 * t + 1]);
        float c = fast_exp2(S1[2 * t]), d = fast_exp2(S1[2 * t + 1]);
        ls0 += a + b;
        ls1 += c + d;
        pk[t]     = pack_bf16(a, b);
        pk[8 + t] = pack_bf16(c, d);
      }

      // O^T += V^T @ P^T  (B-frags via lane^32 half-swap)
#pragma unroll
      for (int g = 0; g < 4; g++) {
        const int base = (g >> 1) * 8 + (g & 1) * 4;
        bf16_8 F = half_swap(pk[base], pk[base + 1], pk[base + 2], pk[base + 3], lhi, xl);
        bf16_8 va0 = *(const bf16_8*)(&Vs[l31 * 136 + hf * 64 + g * 16 + lhi * 8]);
        bf16_8 va1 = *(const bf16_8*)(&Vs[(32 + l31) * 136 + hf * 64 + g * 16 + lhi * 8]);
        O0 = __builtin_amdgcn_mfma_f32_32x32x16_bf16(va0, F, O0, 0, 0, 0);
        O1 = __builtin_amdgcn_mfma_f32_32x32x16_bf16(va1, F, O1, 0, 0, 0);
      }
    }
  }

  float lsum = ls0 + ls1;
  lsum += __shfl_xor(lsum, 32, 64);     // partner lane holds other half-keys
  const float inv = 1.f / lsum;

  // Epilogue: O^T -> per-wave LDS [q][d] (pitch 68) -> coalesced z write
  __syncthreads();                       // all waves done with Ks/Vs
  __bf16* ow = SMEM + wave * (32 * 68);  // 8 waves x 4352 B = 34816 <= 35840
#pragma unroll
  for (int g = 0; g < 4; g++) {
    bf16_4 p0, p1;
#pragma unroll
    for (int i = 0; i < 4; i++) {
      p0[i] = (__bf16)(O0[4 * g + i] * inv);
      p1[i] = (__bf16)(O1[4 * g + i] * inv);
    }
    const int d0 = 8 * g + 4 * lhi;
    *(bf16_4*)(ow + l31 * 68 + d0)      = p0;
    *(bf16_4*)(ow + l31 * 68 + 32 + d0) = p1;
  }
  // wave-private region, DS in-order: no barrier
  const int b = bh >> 3, h = bh & 7;
  const int qr = lane >> 1, c0 = (lane & 1) * 32;
  __bf16* zp = z + ((size_t)b * NN + q0 + qr) * HD + h * DD + c0;
#pragma unroll
  for (int j = 0; j < 4; j++) {
    *(bf16_8*)(zp + 8 * j) = *(const bf16_8*)(ow + qr * 68 + c0 + 8 * j);
  }
}

// ---------------------------------------------------------------------------
// Kernel 3: out projection, k-split x4. Block = 4 waves, one 32-row tile;
// wave w covers k in [w*128, w*128+128). Partials reduced through LDS.
// Grid 512 -> 2048 waves (2/SIMD).
// ---------------------------------------------------------------------------
__global__ __launch_bounds__(256) void out_proj_kernel(
    const __bf16* __restrict__ z, const __bf16* __restrict__ Wob,
    const float* __restrict__ bout, float* __restrict__ out) {
  __shared__ float red[3][64][33];
  const int tid  = threadIdx.x;
  const int wave = tid >> 6, lane = tid & 63;
  const int l31  = lane & 31, lhi = lane >> 5;
  const int row0 = blockIdx.x * 32;

  const __bf16* zr = z + (size_t)(row0 + l31) * HD + wave * 128 + lhi * 8;

  f32_16 C0, C1;
#pragma unroll
  for (int i = 0; i < 16; i++) { C0[i] = 0.f; C1[i] = 0.f; }

#pragma unroll
  for (int s = 0; s < 8; s++) {
    const int sa = wave * 8 + s;        // absolute k-step
    bf16_8 a  = *(const bf16_8*)(zr + s * 16);
    bf16_8 b0 = *(const bf16_8*)(Wob + ((size_t)((0 * 32 + sa) * 64 + lane)) * 8);
    bf16_8 b1 = *(const bf16_8*)(Wob + ((size_t)((1 * 32 + sa) * 64 + lane)) * 8);
    C0 = __builtin_amdgcn_mfma_f32_32x32x16_bf16(a, b0, C0, 0, 0, 0);
    C1 = __builtin_amdgcn_mfma_f32_32x32x16_bf16(a, b1, C1, 0, 0, 0);
  }

  if (wave) {
    float* rw = &red[wave - 1][lane][0];
#pragma unroll
    for (int r = 0; r < 16; r++) { rw[r] = C0[r]; rw[16 + r] = C1[r]; }
  }
  __syncthreads();
  if (wave == 0) {
    const float bi0 = bout[l31], bi1 = bout[32 + l31];
#pragma unroll
    for (int r = 0; r < 16; r++) {
      int n = row0 + (r & 3) + 8 * (r >> 2) + 4 * lhi;
      float v0 = C0[r] + red[0][lane][r]      + red[1][lane][r]      + red[2][lane][r];
      float v1 = C1[r] + red[0][lane][16 + r] + red[1][lane][16 + r] + red[2][lane][16 + r];
      out[(size_t)n * 64 + l31]      = v0 + bi0;
      out[(size_t)n * 64 + 32 + l31] = v1 + bi1;
    }
  }
}

// ---------------------------------------------------------------------------
extern "C" void kernel_launch(void* const* d_in, const int* in_sizes, int n_in,
                              void* d_out, int out_size, void* d_ws, size_t ws_size,
                              hipStream_t stream) {
  const float* x    = (const float*)d_in[0];
  const float* Wqkv = (const float*)d_in[1];
  const float* Wout = (const float*)d_in[2];
  const float* bout = (const float*)d_in[3];
  float* out = (float*)d_out;

  const size_t buf_elems = (size_t)BB * HH * NN * DD;  // 8388608
  __bf16* Qw  = (__bf16*)d_ws;
  __bf16* Kw  = Qw  + buf_elems;
  __bf16* Vtw = Kw  + buf_elems;
  __bf16* zw  = Vtw + buf_elems;
  __bf16* Wob = zw  + buf_elems;       // 32768 bf16

  qkv_kernel<<<dim3(QKV_COLS / 64, NROWS / 128 + 1), 256, 0, stream>>>(
      x, Wqkv, Wout, Qw, Kw, Vtw, Wob);
  attn_kernel<<<BH * (NN / 256), 512, 0, stream>>>(Qw, Kw, Vtw, zw);
  out_proj_kernel<<<NROWS / 32, 256, 0, stream>>>(zw, Wob, bout, out);
}

// Round 7
// 188.659 us; speedup vs baseline: 1.8182x; 1.1683x over previous
//
#include <hip/hip_runtime.h>
#include <math.h>

// Problem constants: B=8, N=2048, DIM=64, H=8
#define BB 8
#define NN 2048
#define DD 64
#define HH 8
#define BH (BB*HH)       // 64
#define HD (HH*DD)       // 512
#define NROWS (BB*NN)    // 16384
#define QKV_COLS (3*HD)  // 1536

typedef __bf16 bf16_8 __attribute__((ext_vector_type(8)));
typedef __bf16 bf16_4 __attribute__((ext_vector_type(4)));
typedef float  f32_16 __attribute__((ext_vector_type(16)));
typedef float  f32_4  __attribute__((ext_vector_type(4)));
typedef int    i32_2  __attribute__((ext_vector_type(2)));

#define QSCALE 0.180336880111f   // 0.125 * log2(e), folded into Q

__device__ __forceinline__ unsigned pack_bf16(float a, float b) {
  union { __bf16 h[2]; unsigned u; } t;
  t.h[0] = (__bf16)a; t.h[1] = (__bf16)b;
  return t.u;
}

__device__ __forceinline__ float fast_exp2(float x) {
#if __has_builtin(__builtin_amdgcn_exp2f)
  return __builtin_amdgcn_exp2f(x);      // raw v_exp_f32
#else
  return __expf(x * 0.69314718056f);
#endif
}

// half-swap across the lane-32 boundary: C-layout row-spread -> A/B-operand
// k-spread (verified rounds 3-6)
__device__ __forceinline__ bf16_8 half_swap(unsigned a0, unsigned a1,
                                            unsigned a2, unsigned a3,
                                            int lhi, int xl) {
  union { unsigned u[4]; bf16_8 v; } F;
#if __has_builtin(__builtin_amdgcn_permlane32_swap)
  i32_2 r02 = __builtin_amdgcn_permlane32_swap((int)a0, (int)a2, false, false);
  i32_2 r13 = __builtin_amdgcn_permlane32_swap((int)a1, (int)a3, false, false);
  F.u[0] = (unsigned)r02.x; F.u[2] = (unsigned)r02.y;
  F.u[1] = (unsigned)r13.x; F.u[3] = (unsigned)r13.y;
#else
  unsigned w0 = (unsigned)__shfl((int)a0, xl, 64);
  unsigned w1 = (unsigned)__shfl((int)a1, xl, 64);
  unsigned w2 = (unsigned)__shfl((int)a2, xl, 64);
  unsigned w3 = (unsigned)__shfl((int)a3, xl, 64);
  F.u[0] = lhi ? w2 : a0;
  F.u[1] = lhi ? w3 : a1;
  F.u[2] = lhi ? a2 : w0;
  F.u[3] = lhi ? a3 : w1;
#endif
  return F.v;
}

// ---------------------------------------------------------------------------
// Kernel 1: QKV projection via MFMA, reading W_qkv fp32 directly (no weight
// prep kernel). V written TRANSPOSED via per-wave LDS tile. The extra grid
// row (blockIdx.y == NROWS/128) converts Wout -> Wob B-fragment layout:
//   Wob[((t*32 + s)*64 + lane)*8 + j] = Wout[s*16 + (lane>>5)*8 + j][t*32 + (lane&31)]
// ---------------------------------------------------------------------------
__global__ __launch_bounds__(256) void qkv_kernel(
    const float* __restrict__ x, const float* __restrict__ Wqkv,
    const float* __restrict__ Wout,
    __bf16* __restrict__ Q, __bf16* __restrict__ K, __bf16* __restrict__ Vt,
    __bf16* __restrict__ Wob) {
  __shared__ __bf16 T[4][64][34];       // per-wave transpose tile (+2 pad)

  if (blockIdx.y == (NROWS / 128)) {    // weight-prep row (24 blocks)
    int id = blockIdx.x * 256 + threadIdx.x;   // 0..6143
    for (int e = id; e < 512 * 64; e += 24 * 256) {
      int kf = e >> 6, col = e & 63;
      int s = kf >> 4, lh = (kf >> 3) & 1, j = kf & 7;
      int t = col >> 5, lc = col & 31;
      Wob[((size_t)((t * 32 + s) * 64 + lh * 32 + lc)) * 8 + j] = (__bf16)Wout[e];
    }
    return;
  }

  const int lane = threadIdx.x & 63;
  const int wave = threadIdx.x >> 6;
  const int l31  = lane & 31, lhi = lane >> 5;
  const int cg   = blockIdx.x;                    // 0..23 (64-col group)
  const int row0 = blockIdx.y * 128 + wave * 32;

  // A-frags: A[m=l31][k = s*16 + lhi*8 + j], fp32 -> bf16
  const float* xr = x + (size_t)(row0 + l31) * 64 + lhi * 8;
  bf16_8 af[4];
#pragma unroll
  for (int s = 0; s < 4; s++) {
    f32_4 a0 = *(const f32_4*)(xr + s * 16);
    f32_4 a1 = *(const f32_4*)(xr + s * 16 + 4);
#pragma unroll
    for (int j = 0; j < 4; j++) { af[s][j] = (__bf16)a0[j]; af[s][4 + j] = (__bf16)a1[j]; }
  }

  const int col0  = cg * 64;
  const int which = col0 >> 9;          // 0=Q 1=K 2=V
  const float wscl = (which == 0) ? QSCALE : 1.0f;

  f32_16 C0, C1;
#pragma unroll
  for (int i = 0; i < 16; i++) { C0[i] = 0.f; C1[i] = 0.f; }

  // B-frags read directly from fp32 Wqkv[k][1536]: lanes consecutive cols
#pragma unroll
  for (int s = 0; s < 4; s++) {
    bf16_8 b0, b1;
#pragma unroll
    for (int j = 0; j < 8; j++) {
      int k = s * 16 + lhi * 8 + j;
      b0[j] = (__bf16)(Wqkv[(size_t)k * QKV_COLS + col0 + l31]      * wscl);
      b1[j] = (__bf16)(Wqkv[(size_t)k * QKV_COLS + col0 + 32 + l31] * wscl);
    }
    C0 = __builtin_amdgcn_mfma_f32_32x32x16_bf16(af[s], b0, C0, 0, 0, 0);
    C1 = __builtin_amdgcn_mfma_f32_32x32x16_bf16(af[s], b1, C1, 0, 0, 0);
  }

  const int h   = (col0 >> 6) & 7;
  const int b   = row0 >> 11;
  const int n0l = row0 & 2047;

  if (which < 2) {
    __bf16* dst = (which == 0) ? Q : K;
#pragma unroll
    for (int r = 0; r < 16; r++) {
      int nl = (r & 3) + 8 * (r >> 2) + 4 * lhi;
      size_t base = (((size_t)(b * HH + h) * NN) + n0l + nl) * DD;
      dst[base + l31]      = (__bf16)C0[r];
      dst[base + 32 + l31] = (__bf16)C1[r];
    }
  } else {
    // transpose 32n x 64d -> Vt[bh][d][n]  (wave-private tile, no barrier)
    __bf16 (*Tw)[34] = T[wave];
#pragma unroll
    for (int r = 0; r < 16; r++) {
      int nl = (r & 3) + 8 * (r >> 2) + 4 * lhi;
      Tw[l31][nl]      = (__bf16)C0[r];
      Tw[32 + l31][nl] = (__bf16)C1[r];
    }
    __bf16* dst = Vt + (((size_t)(b * HH + h) * DD) + lane) * NN + n0l;
#pragma unroll
    for (int j = 0; j < 4; j++) {
      *(bf16_8*)(dst + j * 8) = *(const bf16_8*)(&Tw[lane][j * 8]);
    }
  }
}

// ---------------------------------------------------------------------------
// Kernel 2: flash attention, 8-wave blocks (512 thr), 256 queries/block,
// K-tile = 128 staged in LDS (shared by all 8 waves), reg-prefetch pipeline,
// S^T formulation with in-register P^T, exp2.
// NOTE: plain __launch_bounds__(512) — round 6's (512,4) made the compiler
// clamp to 64 VGPR and spill ~262 MB/dispatch to scratch (WRITE_SIZE 271 MB).
// ~110-130 VGPR -> 4 waves/SIMD (2 blocks/CU) without spill.
// ---------------------------------------------------------------------------
__global__ __launch_bounds__(512) void attn_kernel(
    const __bf16* __restrict__ Q, const __bf16* __restrict__ K,
    const __bf16* __restrict__ Vt, __bf16* __restrict__ z) {
  __shared__ __bf16 SMEM[128 * 72 + 64 * 136];   // Ks | Vs = 35840 B
  __bf16* Ks = SMEM;                    // [key][d], pitch 72
  __bf16* Vs = SMEM + 128 * 72;         // [d][key], pitch 136

  const int tid  = threadIdx.x;
  const int wave = tid >> 6;
  const int lane = tid & 63;
  const int l31  = lane & 31;
  const int lhi  = lane >> 5;
  const int xl   = lane ^ 32;
  const int bh   = blockIdx.x >> 3;                     // 0..63
  const int q0   = (blockIdx.x & 7) * 256 + wave * 32;  // 32 queries/wave

  // Q fragments (B-operand: n=query=l31, k = s*16 + lhi*8 + j)
  const __bf16* Qbase = Q + ((size_t)bh * NN + q0 + l31) * DD + lhi * 8;
  bf16_8 qf[4];
#pragma unroll
  for (int s = 0; s < 4; s++) qf[s] = *(const bf16_8*)(Qbase + s * 16);

  f32_16 O0, O1;
#pragma unroll
  for (int i = 0; i < 16; i++) { O0[i] = 0.f; O1[i] = 0.f; }
  float ls0 = 0.f, ls1 = 0.f;

  const __bf16* Kb = K  + (size_t)bh * NN * DD;
  const __bf16* Vb = Vt + (size_t)bh * DD * NN;

  // staging split across 512 threads: 2 b128 each for K and V
  const int krow = tid >> 3, kcol = (tid & 7) * 8;    // K: 128 x 64, 64 rows/pass
  const int vrow = tid >> 4, vcol = (tid & 15) * 8;   // V: 64 x 128, 32 rows/pass
  const __bf16* kgl = Kb + (size_t)krow * 64 + kcol;
  const __bf16* vgl = Vb + (size_t)vrow * NN + vcol;
  __bf16* klds = &Ks[krow * 72 + kcol];
  __bf16* vlds = &Vs[vrow * 136 + vcol];

  bf16_8 gk[2], gv[2];
#pragma unroll
  for (int i = 0; i < 2; i++) {
    gk[i] = *(const bf16_8*)(kgl + (size_t)i * 64 * 64);
    gv[i] = *(const bf16_8*)(vgl + (size_t)i * 32 * NN);
  }

  for (int kt = 0; kt < NN; kt += 128) {
    __syncthreads();
#pragma unroll
    for (int i = 0; i < 2; i++) {
      *(bf16_8*)(klds + i * 64 * 72)  = gk[i];
      *(bf16_8*)(vlds + i * 32 * 136) = gv[i];
    }
    __syncthreads();
    if (kt + 128 < NN) {                 // prefetch next tile into regs
#pragma unroll
      for (int i = 0; i < 2; i++) {
        gk[i] = *(const bf16_8*)(kgl + (size_t)(kt + 128) * 64 + (size_t)i * 64 * 64);
        gv[i] = *(const bf16_8*)(vgl + (kt + 128) + (size_t)i * 32 * NN);
      }
    }

#pragma unroll
    for (int hf = 0; hf < 2; hf++) {     // two 64-key halves of the tile
      // S^T = K @ Q^T
      f32_16 S0, S1;
#pragma unroll
      for (int i = 0; i < 16; i++) { S0[i] = 0.f; S1[i] = 0.f; }
#pragma unroll
      for (int s = 0; s < 4; s++) {
        bf16_8 kb0 = *(const bf16_8*)(&Ks[(hf * 64 + l31) * 72 + s * 16 + lhi * 8]);
        bf16_8 kb1 = *(const bf16_8*)(&Ks[(hf * 64 + 32 + l31) * 72 + s * 16 + lhi * 8]);
        S0 = __builtin_amdgcn_mfma_f32_32x32x16_bf16(kb0, qf[s], S0, 0, 0, 0);
        S1 = __builtin_amdgcn_mfma_f32_32x32x16_bf16(kb1, qf[s], S1, 0, 0, 0);
      }

      // P^T = exp2(S^T)  (log2(e)/8 folded into Q)
      unsigned pk[16];
#pragma unroll
      for (int t = 0; t < 8; t++) {
        float a = fast_exp2(S0[2 * t]), b = fast_exp2(S0[2 * t + 1]);
        float c = fast_exp2(S1[2 * t]), d = fast_exp2(S1[2 * t + 1]);
        ls0 += a + b;
        ls1 += c + d;
        pk[t]     = pack_bf16(a, b);
        pk[8 + t] = pack_bf16(c, d);
      }

      // O^T += V^T @ P^T  (B-frags via lane^32 half-swap)
#pragma unroll
      for (int g = 0; g < 4; g++) {
        const int base = (g >> 1) * 8 + (g & 1) * 4;
        bf16_8 F = half_swap(pk[base], pk[base + 1], pk[base + 2], pk[base + 3], lhi, xl);
        bf16_8 va0 = *(const bf16_8*)(&Vs[l31 * 136 + hf * 64 + g * 16 + lhi * 8]);
        bf16_8 va1 = *(const bf16_8*)(&Vs[(32 + l31) * 136 + hf * 64 + g * 16 + lhi * 8]);
        O0 = __builtin_amdgcn_mfma_f32_32x32x16_bf16(va0, F, O0, 0, 0, 0);
        O1 = __builtin_amdgcn_mfma_f32_32x32x16_bf16(va1, F, O1, 0, 0, 0);
      }
    }
  }

  float lsum = ls0 + ls1;
  lsum += __shfl_xor(lsum, 32, 64);     // partner lane holds other half-keys
  const float inv = 1.f / lsum;

  // Epilogue: O^T -> per-wave LDS [q][d] (pitch 68) -> coalesced z write
  __syncthreads();                       // all waves done with Ks/Vs
  __bf16* ow = SMEM + wave * (32 * 68);  // 8 waves x 4352 B = 34816 <= 35840
#pragma unroll
  for (int g = 0; g < 4; g++) {
    bf16_4 p0, p1;
#pragma unroll
    for (int i = 0; i < 4; i++) {
      p0[i] = (__bf16)(O0[4 * g + i] * inv);
      p1[i] = (__bf16)(O1[4 * g + i] * inv);
    }
    const int d0 = 8 * g + 4 * lhi;
    *(bf16_4*)(ow + l31 * 68 + d0)      = p0;
    *(bf16_4*)(ow + l31 * 68 + 32 + d0) = p1;
  }
  // wave-private region, DS in-order: no barrier
  const int b = bh >> 3, h = bh & 7;
  const int qr = lane >> 1, c0 = (lane & 1) * 32;
  __bf16* zp = z + ((size_t)b * NN + q0 + qr) * HD + h * DD + c0;
#pragma unroll
  for (int j = 0; j < 4; j++) {
    *(bf16_8*)(zp + 8 * j) = *(const bf16_8*)(ow + qr * 68 + c0 + 8 * j);
  }
}

// ---------------------------------------------------------------------------
// Kernel 3: out projection, k-split x4. Block = 4 waves, one 32-row tile;
// wave w covers k in [w*128, w*128+128). Partials reduced through LDS.
// Grid 512 -> 2048 waves (2/SIMD).
// ---------------------------------------------------------------------------
__global__ __launch_bounds__(256) void out_proj_kernel(
    const __bf16* __restrict__ z, const __bf16* __restrict__ Wob,
    const float* __restrict__ bout, float* __restrict__ out) {
  __shared__ float red[3][64][33];
  const int tid  = threadIdx.x;
  const int wave = tid >> 6, lane = tid & 63;
  const int l31  = lane & 31, lhi = lane >> 5;
  const int row0 = blockIdx.x * 32;

  const __bf16* zr = z + (size_t)(row0 + l31) * HD + wave * 128 + lhi * 8;

  f32_16 C0, C1;
#pragma unroll
  for (int i = 0; i < 16; i++) { C0[i] = 0.f; C1[i] = 0.f; }

#pragma unroll
  for (int s = 0; s < 8; s++) {
    const int sa = wave * 8 + s;        // absolute k-step
    bf16_8 a  = *(const bf16_8*)(zr + s * 16);
    bf16_8 b0 = *(const bf16_8*)(Wob + ((size_t)((0 * 32 + sa) * 64 + lane)) * 8);
    bf16_8 b1 = *(const bf16_8*)(Wob + ((size_t)((1 * 32 + sa) * 64 + lane)) * 8);
    C0 = __builtin_amdgcn_mfma_f32_32x32x16_bf16(a, b0, C0, 0, 0, 0);
    C1 = __builtin_amdgcn_mfma_f32_32x32x16_bf16(a, b1, C1, 0, 0, 0);
  }

  if (wave) {
    float* rw = &red[wave - 1][lane][0];
#pragma unroll
    for (int r = 0; r < 16; r++) { rw[r] = C0[r]; rw[16 + r] = C1[r]; }
  }
  __syncthreads();
  if (wave == 0) {
    const float bi0 = bout[l31], bi1 = bout[32 + l31];
#pragma unroll
    for (int r = 0; r < 16; r++) {
      int n = row0 + (r & 3) + 8 * (r >> 2) + 4 * lhi;
      float v0 = C0[r] + red[0][lane][r]      + red[1][lane][r]      + red[2][lane][r];
      float v1 = C1[r] + red[0][lane][16 + r] + red[1][lane][16 + r] + red[2][lane][16 + r];
      out[(size_t)n * 64 + l31]      = v0 + bi0;
      out[(size_t)n * 64 + 32 + l31] = v1 + bi1;
    }
  }
}

// ---------------------------------------------------------------------------
extern "C" void kernel_launch(void* const* d_in, const int* in_sizes, int n_in,
                              void* d_out, int out_size, void* d_ws, size_t ws_size,
                              hipStream_t stream) {
  const float* x    = (const float*)d_in[0];
  const float* Wqkv = (const float*)d_in[1];
  const float* Wout = (const float*)d_in[2];
  const float* bout = (const float*)d_in[3];
  float* out = (float*)d_out;

  const size_t buf_elems = (size_t)BB * HH * NN * DD;  // 8388608
  __bf16* Qw  = (__bf16*)d_ws;
  __bf16* Kw  = Qw  + buf_elems;
  __bf16* Vtw = Kw  + buf_elems;
  __bf16* zw  = Vtw + buf_elems;
  __bf16* Wob = zw  + buf_elems;       // 32768 bf16

  qkv_kernel<<<dim3(QKV_COLS / 64, NROWS / 128 + 1), 256, 0, stream>>>(
      x, Wqkv, Wout, Qw, Kw, Vtw, Wob);
  attn_kernel<<<BH * (NN / 256), 512, 0, stream>>>(Qw, Kw, Vtw, zw);
  out_proj_kernel<<<NROWS / 32, 256, 0, stream>>>(zw, Wob, bout, out);
}

// Round 8
// 181.948 us; speedup vs baseline: 1.8853x; 1.0369x over previous
//
#include <hip/hip_runtime.h>
#include <math.h>

// Problem constants: B=8, N=2048, DIM=64, H=8
#define BB 8
#define NN 2048
#define DD 64
#define HH 8
#define BH (BB*HH)       // 64
#define HD (HH*DD)       // 512
#define NROWS (BB*NN)    // 16384
#define QKV_COLS (3*HD)  // 1536

typedef __bf16 bf16_8 __attribute__((ext_vector_type(8)));
typedef __bf16 bf16_4 __attribute__((ext_vector_type(4)));
typedef float  f32_16 __attribute__((ext_vector_type(16)));
typedef float  f32_4  __attribute__((ext_vector_type(4)));
typedef int    i32_2  __attribute__((ext_vector_type(2)));

#define QSCALE 0.180336880111f   // 0.125 * log2(e), folded into Q

__device__ __forceinline__ unsigned pack_bf16(float a, float b) {
  union { __bf16 h[2]; unsigned u; } t;
  t.h[0] = (__bf16)a; t.h[1] = (__bf16)b;
  return t.u;
}

__device__ __forceinline__ float fast_exp2(float x) {
#if __has_builtin(__builtin_amdgcn_exp2f)
  return __builtin_amdgcn_exp2f(x);      // raw v_exp_f32
#else
  return __expf(x * 0.69314718056f);
#endif
}

// half-swap across the lane-32 boundary: C-layout row-spread -> A/B-operand
// k-spread (verified rounds 3-7)
__device__ __forceinline__ bf16_8 half_swap(unsigned a0, unsigned a1,
                                            unsigned a2, unsigned a3,
                                            int lhi, int xl) {
  union { unsigned u[4]; bf16_8 v; } F;
#if __has_builtin(__builtin_amdgcn_permlane32_swap)
  i32_2 r02 = __builtin_amdgcn_permlane32_swap((int)a0, (int)a2, false, false);
  i32_2 r13 = __builtin_amdgcn_permlane32_swap((int)a1, (int)a3, false, false);
  F.u[0] = (unsigned)r02.x; F.u[2] = (unsigned)r02.y;
  F.u[1] = (unsigned)r13.x; F.u[3] = (unsigned)r13.y;
#else
  unsigned w0 = (unsigned)__shfl((int)a0, xl, 64);
  unsigned w1 = (unsigned)__shfl((int)a1, xl, 64);
  unsigned w2 = (unsigned)__shfl((int)a2, xl, 64);
  unsigned w3 = (unsigned)__shfl((int)a3, xl, 64);
  F.u[0] = lhi ? w2 : a0;
  F.u[1] = lhi ? w3 : a1;
  F.u[2] = lhi ? a2 : w0;
  F.u[3] = lhi ? a3 : w1;
#endif
  return F.v;
}

// ---------------------------------------------------------------------------
// Kernel 1: QKV projection via MFMA, reading W_qkv fp32 directly. V written
// TRANSPOSED via per-wave LDS tile. Extra grid row preps Wout -> Wob
// B-fragment layout for out_proj.
// ---------------------------------------------------------------------------
__global__ __launch_bounds__(256) void qkv_kernel(
    const float* __restrict__ x, const float* __restrict__ Wqkv,
    const float* __restrict__ Wout,
    __bf16* __restrict__ Q, __bf16* __restrict__ K, __bf16* __restrict__ Vt,
    __bf16* __restrict__ Wob) {
  __shared__ __bf16 T[4][64][34];       // per-wave transpose tile (+2 pad)

  if (blockIdx.y == (NROWS / 128)) {    // weight-prep row (24 blocks)
    int id = blockIdx.x * 256 + threadIdx.x;   // 0..6143
    for (int e = id; e < 512 * 64; e += 24 * 256) {
      int kf = e >> 6, col = e & 63;
      int s = kf >> 4, lh = (kf >> 3) & 1, j = kf & 7;
      int t = col >> 5, lc = col & 31;
      Wob[((size_t)((t * 32 + s) * 64 + lh * 32 + lc)) * 8 + j] = (__bf16)Wout[e];
    }
    return;
  }

  const int lane = threadIdx.x & 63;
  const int wave = threadIdx.x >> 6;
  const int l31  = lane & 31, lhi = lane >> 5;
  const int cg   = blockIdx.x;                    // 0..23 (64-col group)
  const int row0 = blockIdx.y * 128 + wave * 32;

  // A-frags: A[m=l31][k = s*16 + lhi*8 + j], fp32 -> bf16
  const float* xr = x + (size_t)(row0 + l31) * 64 + lhi * 8;
  bf16_8 af[4];
#pragma unroll
  for (int s = 0; s < 4; s++) {
    f32_4 a0 = *(const f32_4*)(xr + s * 16);
    f32_4 a1 = *(const f32_4*)(xr + s * 16 + 4);
#pragma unroll
    for (int j = 0; j < 4; j++) { af[s][j] = (__bf16)a0[j]; af[s][4 + j] = (__bf16)a1[j]; }
  }

  const int col0  = cg * 64;
  const int which = col0 >> 9;          // 0=Q 1=K 2=V
  const float wscl = (which == 0) ? QSCALE : 1.0f;

  f32_16 C0, C1;
#pragma unroll
  for (int i = 0; i < 16; i++) { C0[i] = 0.f; C1[i] = 0.f; }

  // B-frags read directly from fp32 Wqkv[k][1536]: lanes consecutive cols
#pragma unroll
  for (int s = 0; s < 4; s++) {
    bf16_8 b0, b1;
#pragma unroll
    for (int j = 0; j < 8; j++) {
      int k = s * 16 + lhi * 8 + j;
      b0[j] = (__bf16)(Wqkv[(size_t)k * QKV_COLS + col0 + l31]      * wscl);
      b1[j] = (__bf16)(Wqkv[(size_t)k * QKV_COLS + col0 + 32 + l31] * wscl);
    }
    C0 = __builtin_amdgcn_mfma_f32_32x32x16_bf16(af[s], b0, C0, 0, 0, 0);
    C1 = __builtin_amdgcn_mfma_f32_32x32x16_bf16(af[s], b1, C1, 0, 0, 0);
  }

  const int h   = (col0 >> 6) & 7;
  const int b   = row0 >> 11;
  const int n0l = row0 & 2047;

  if (which < 2) {
    __bf16* dst = (which == 0) ? Q : K;
#pragma unroll
    for (int r = 0; r < 16; r++) {
      int nl = (r & 3) + 8 * (r >> 2) + 4 * lhi;
      size_t base = (((size_t)(b * HH + h) * NN) + n0l + nl) * DD;
      dst[base + l31]      = (__bf16)C0[r];
      dst[base + 32 + l31] = (__bf16)C1[r];
    }
  } else {
    // transpose 32n x 64d -> Vt[bh][d][n]  (wave-private tile, no barrier)
    __bf16 (*Tw)[34] = T[wave];
#pragma unroll
    for (int r = 0; r < 16; r++) {
      int nl = (r & 3) + 8 * (r >> 2) + 4 * lhi;
      Tw[l31][nl]      = (__bf16)C0[r];
      Tw[32 + l31][nl] = (__bf16)C1[r];
    }
    __bf16* dst = Vt + (((size_t)(b * HH + h) * DD) + lane) * NN + n0l;
#pragma unroll
    for (int j = 0; j < 4; j++) {
      *(bf16_8*)(dst + j * 8) = *(const bf16_8*)(&Tw[lane][j * 8]);
    }
  }
}

// ---------------------------------------------------------------------------
// Kernel 2: flash attention, 8-wave blocks, K-tile=128, DOUBLE-BUFFERED LDS
// with ONE barrier per iteration: tile i+1 is written to the other buffer
// from prefetched regs (loads issued a full compute-phase earlier) BEFORE
// compute, so the barrier covers only wave skew — no vmcnt/lgkm drain on
// the critical path. Plain __launch_bounds__(512): (512,4) caused a 64-VGPR
// clamp + 262 MB scratch spill in round 6.
// ---------------------------------------------------------------------------
#define TILE_ELEMS (128 * 72 + 64 * 136)   // 17920 bf16 = 35840 B per buffer
__global__ __launch_bounds__(512) void attn_kernel(
    const __bf16* __restrict__ Q, const __bf16* __restrict__ K,
    const __bf16* __restrict__ Vt, __bf16* __restrict__ z) {
  __shared__ __bf16 SMEM[2][TILE_ELEMS];   // 71680 B -> 2 blocks/CU

  const int tid  = threadIdx.x;
  const int wave = tid >> 6;
  const int lane = tid & 63;
  const int l31  = lane & 31;
  const int lhi  = lane >> 5;
  const int xl   = lane ^ 32;
  const int bh   = blockIdx.x >> 3;                     // 0..63
  const int q0   = (blockIdx.x & 7) * 256 + wave * 32;  // 32 queries/wave

  // Q fragments (B-operand: n=query=l31, k = s*16 + lhi*8 + j)
  const __bf16* Qbase = Q + ((size_t)bh * NN + q0 + l31) * DD + lhi * 8;
  bf16_8 qf[4];
#pragma unroll
  for (int s = 0; s < 4; s++) qf[s] = *(const bf16_8*)(Qbase + s * 16);

  f32_16 O0, O1;
#pragma unroll
  for (int i = 0; i < 16; i++) { O0[i] = 0.f; O1[i] = 0.f; }
  float ls0 = 0.f, ls1 = 0.f;

  const __bf16* Kb = K  + (size_t)bh * NN * DD;
  const __bf16* Vb = Vt + (size_t)bh * DD * NN;

  // staging split across 512 threads: 2 b128 each for K and V per tile
  const int krow = tid >> 3, kcol = (tid & 7) * 8;    // K: 128 x 64
  const int vrow = tid >> 4, vcol = (tid & 15) * 8;   // V: 64 x 128
  const __bf16* kgl = Kb + (size_t)krow * 64 + kcol;
  const __bf16* vgl = Vb + (size_t)vrow * NN + vcol;
  const int koff0 = krow * 72 + kcol;
  const int voff0 = 128 * 72 + vrow * 136 + vcol;

  bf16_8 gk[2], gv[2];
  // load tile 0
#pragma unroll
  for (int i = 0; i < 2; i++) {
    gk[i] = *(const bf16_8*)(kgl + (size_t)i * 64 * 64);
    gv[i] = *(const bf16_8*)(vgl + (size_t)i * 32 * NN);
  }
  // stage tile 0 into buf0
  {
    __bf16* S = SMEM[0];
    *(bf16_8*)(S + koff0)            = gk[0];
    *(bf16_8*)(S + koff0 + 64 * 72)  = gk[1];
    *(bf16_8*)(S + voff0)            = gv[0];
    *(bf16_8*)(S + voff0 + 32 * 136) = gv[1];
  }
  // issue loads for tile 1
#pragma unroll
  for (int i = 0; i < 2; i++) {
    gk[i] = *(const bf16_8*)(kgl + (size_t)128 * 64 + (size_t)i * 64 * 64);
    gv[i] = *(const bf16_8*)(vgl + 128 + (size_t)i * 32 * NN);
  }
  __syncthreads();

  for (int it = 0; it < 16; it++) {
    __bf16* Ks = SMEM[it & 1];
    __bf16* Vs = SMEM[it & 1] + 128 * 72;

    // stage tile it+1 into the OTHER buffer before compute
    if (it < 15) {
      __bf16* Sn = SMEM[(it + 1) & 1];
      *(bf16_8*)(Sn + koff0)            = gk[0];
      *(bf16_8*)(Sn + koff0 + 64 * 72)  = gk[1];
      *(bf16_8*)(Sn + voff0)            = gv[0];
      *(bf16_8*)(Sn + voff0 + 32 * 136) = gv[1];
      if (it < 14) {                     // issue loads for tile it+2
        const size_t kadv = (size_t)(it + 2) * 128 * 64;
        const size_t vadv = (size_t)(it + 2) * 128;
#pragma unroll
        for (int i = 0; i < 2; i++) {
          gk[i] = *(const bf16_8*)(kgl + kadv + (size_t)i * 64 * 64);
          gv[i] = *(const bf16_8*)(vgl + vadv + (size_t)i * 32 * NN);
        }
      }
    }

#pragma unroll
    for (int hf = 0; hf < 2; hf++) {     // two 64-key halves of the tile
      // S^T = K @ Q^T
      f32_16 S0, S1;
#pragma unroll
      for (int i = 0; i < 16; i++) { S0[i] = 0.f; S1[i] = 0.f; }
#pragma unroll
      for (int s = 0; s < 4; s++) {
        bf16_8 kb0 = *(const bf16_8*)(&Ks[(hf * 64 + l31) * 72 + s * 16 + lhi * 8]);
        bf16_8 kb1 = *(const bf16_8*)(&Ks[(hf * 64 + 32 + l31) * 72 + s * 16 + lhi * 8]);
        S0 = __builtin_amdgcn_mfma_f32_32x32x16_bf16(kb0, qf[s], S0, 0, 0, 0);
        S1 = __builtin_amdgcn_mfma_f32_32x32x16_bf16(kb1, qf[s], S1, 0, 0, 0);
      }

      // P^T = exp2(S^T)  (log2(e)/8 folded into Q)
      unsigned pk[16];
#pragma unroll
      for (int t = 0; t < 8; t++) {
        float a = fast_exp2(S0[2 * t]), b = fast_exp2(S0[2 * t + 1]);
        float c = fast_exp2(S1[2 * t]), d = fast_exp2(S1[2 * t + 1]);
        ls0 += a + b;
        ls1 += c + d;
        pk[t]     = pack_bf16(a, b);
        pk[8 + t] = pack_bf16(c, d);
      }

      // O^T += V^T @ P^T  (B-frags via lane^32 half-swap)
#pragma unroll
      for (int g = 0; g < 4; g++) {
        const int base = (g >> 1) * 8 + (g & 1) * 4;
        bf16_8 F = half_swap(pk[base], pk[base + 1], pk[base + 2], pk[base + 3], lhi, xl);
        bf16_8 va0 = *(const bf16_8*)(&Vs[l31 * 136 + hf * 64 + g * 16 + lhi * 8]);
        bf16_8 va1 = *(const bf16_8*)(&Vs[(32 + l31) * 136 + hf * 64 + g * 16 + lhi * 8]);
        O0 = __builtin_amdgcn_mfma_f32_32x32x16_bf16(va0, F, O0, 0, 0, 0);
        O1 = __builtin_amdgcn_mfma_f32_32x32x16_bf16(va1, F, O1, 0, 0, 0);
      }
    }
    __syncthreads();   // single barrier: readers of Ks/Vs done, next buf ready
  }

  float lsum = ls0 + ls1;
  lsum += __shfl_xor(lsum, 32, 64);     // partner lane holds other half-keys
  const float inv = 1.f / lsum;

  // Epilogue: O^T -> per-wave LDS [q][d] (pitch 68) -> coalesced z write
  // (loop's final barrier already separates SMEM reuse)
  __bf16* ow = SMEM[0] + wave * (32 * 68);  // 8 x 4352 B = 34816 <= 35840
#pragma unroll
  for (int g = 0; g < 4; g++) {
    bf16_4 p0, p1;
#pragma unroll
    for (int i = 0; i < 4; i++) {
      p0[i] = (__bf16)(O0[4 * g + i] * inv);
      p1[i] = (__bf16)(O1[4 * g + i] * inv);
    }
    const int d0 = 8 * g + 4 * lhi;
    *(bf16_4*)(ow + l31 * 68 + d0)      = p0;
    *(bf16_4*)(ow + l31 * 68 + 32 + d0) = p1;
  }
  // wave-private region, DS in-order: no barrier
  const int b = bh >> 3, h = bh & 7;
  const int qr = lane >> 1, c0 = (lane & 1) * 32;
  __bf16* zp = z + ((size_t)b * NN + q0 + qr) * HD + h * DD + c0;
#pragma unroll
  for (int j = 0; j < 4; j++) {
    *(bf16_8*)(zp + 8 * j) = *(const bf16_8*)(ow + qr * 68 + c0 + 8 * j);
  }
}

// ---------------------------------------------------------------------------
// Kernel 3: out projection, k-split x4. Block = 4 waves, one 32-row tile;
// wave w covers k in [w*128, w*128+128). Partials reduced through LDS.
// ---------------------------------------------------------------------------
__global__ __launch_bounds__(256) void out_proj_kernel(
    const __bf16* __restrict__ z, const __bf16* __restrict__ Wob,
    const float* __restrict__ bout, float* __restrict__ out) {
  __shared__ float red[3][64][33];
  const int tid  = threadIdx.x;
  const int wave = tid >> 6, lane = tid & 63;
  const int l31  = lane & 31, lhi = lane >> 5;
  const int row0 = blockIdx.x * 32;

  const __bf16* zr = z + (size_t)(row0 + l31) * HD + wave * 128 + lhi * 8;

  f32_16 C0, C1;
#pragma unroll
  for (int i = 0; i < 16; i++) { C0[i] = 0.f; C1[i] = 0.f; }

#pragma unroll
  for (int s = 0; s < 8; s++) {
    const int sa = wave * 8 + s;        // absolute k-step
    bf16_8 a  = *(const bf16_8*)(zr + s * 16);
    bf16_8 b0 = *(const bf16_8*)(Wob + ((size_t)((0 * 32 + sa) * 64 + lane)) * 8);
    bf16_8 b1 = *(const bf16_8*)(Wob + ((size_t)((1 * 32 + sa) * 64 + lane)) * 8);
    C0 = __builtin_amdgcn_mfma_f32_32x32x16_bf16(a, b0, C0, 0, 0, 0);
    C1 = __builtin_amdgcn_mfma_f32_32x32x16_bf16(a, b1, C1, 0, 0, 0);
  }

  if (wave) {
    float* rw = &red[wave - 1][lane][0];
#pragma unroll
    for (int r = 0; r < 16; r++) { rw[r] = C0[r]; rw[16 + r] = C1[r]; }
  }
  __syncthreads();
  if (wave == 0) {
    const float bi0 = bout[l31], bi1 = bout[32 + l31];
#pragma unroll
    for (int r = 0; r < 16; r++) {
      int n = row0 + (r & 3) + 8 * (r >> 2) + 4 * lhi;
      float v0 = C0[r] + red[0][lane][r]      + red[1][lane][r]      + red[2][lane][r];
      float v1 = C1[r] + red[0][lane][16 + r] + red[1][lane][16 + r] + red[2][lane][16 + r];
      out[(size_t)n * 64 + l31]      = v0 + bi0;
      out[(size_t)n * 64 + 32 + l31] = v1 + bi1;
    }
  }
}

// ---------------------------------------------------------------------------
extern "C" void kernel_launch(void* const* d_in, const int* in_sizes, int n_in,
                              void* d_out, int out_size, void* d_ws, size_t ws_size,
                              hipStream_t stream) {
  const float* x    = (const float*)d_in[0];
  const float* Wqkv = (const float*)d_in[1];
  const float* Wout = (const float*)d_in[2];
  const float* bout = (const float*)d_in[3];
  float* out = (float*)d_out;

  const size_t buf_elems = (size_t)BB * HH * NN * DD;  // 8388608
  __bf16* Qw  = (__bf16*)d_ws;
  __bf16* Kw  = Qw  + buf_elems;
  __bf16* Vtw = Kw  + buf_elems;
  __bf16* zw  = Vtw + buf_elems;
  __bf16* Wob = zw  + buf_elems;       // 32768 bf16

  qkv_kernel<<<dim3(QKV_COLS / 64, NROWS / 128 + 1), 256, 0, stream>>>(
      x, Wqkv, Wout, Qw, Kw, Vtw, Wob);
  attn_kernel<<<BH * (NN / 256), 512, 0, stream>>>(Qw, Kw, Vtw, zw);
  out_proj_kernel<<<NROWS / 32, 256, 0, stream>>>(zw, Wob, bout, out);
}

// Round 9
// 180.048 us; speedup vs baseline: 1.9052x; 1.0106x over previous
//
#include <hip/hip_runtime.h>
#include <math.h>

// Problem constants: B=8, N=2048, DIM=64, H=8
#define BB 8
#define NN 2048
#define DD 64
#define HH 8
#define BH (BB*HH)       // 64
#define HD (HH*DD)       // 512
#define NROWS (BB*NN)    // 16384
#define QKV_COLS (3*HD)  // 1536

typedef __bf16 bf16_8 __attribute__((ext_vector_type(8)));
typedef __bf16 bf16_4 __attribute__((ext_vector_type(4)));
typedef float  f32_16 __attribute__((ext_vector_type(16)));
typedef float  f32_4  __attribute__((ext_vector_type(4)));
typedef int    i32_2  __attribute__((ext_vector_type(2)));

#define QSCALE 0.180336880111f   // 0.125 * log2(e), folded into Q

__device__ __forceinline__ unsigned pack_bf16(float a, float b) {
  union { __bf16 h[2]; unsigned u; } t;
  t.h[0] = (__bf16)a; t.h[1] = (__bf16)b;
  return t.u;
}

__device__ __forceinline__ float fast_exp2(float x) {
#if __has_builtin(__builtin_amdgcn_exp2f)
  return __builtin_amdgcn_exp2f(x);      // raw v_exp_f32
#else
  return __expf(x * 0.69314718056f);
#endif
}

// half-swap across the lane-32 boundary: C-layout row-spread -> A/B-operand
// k-spread (verified rounds 3-8)
__device__ __forceinline__ bf16_8 half_swap(unsigned a0, unsigned a1,
                                            unsigned a2, unsigned a3,
                                            int lhi, int xl) {
  union { unsigned u[4]; bf16_8 v; } F;
#if __has_builtin(__builtin_amdgcn_permlane32_swap)
  i32_2 r02 = __builtin_amdgcn_permlane32_swap((int)a0, (int)a2, false, false);
  i32_2 r13 = __builtin_amdgcn_permlane32_swap((int)a1, (int)a3, false, false);
  F.u[0] = (unsigned)r02.x; F.u[2] = (unsigned)r02.y;
  F.u[1] = (unsigned)r13.x; F.u[3] = (unsigned)r13.y;
#else
  unsigned w0 = (unsigned)__shfl((int)a0, xl, 64);
  unsigned w1 = (unsigned)__shfl((int)a1, xl, 64);
  unsigned w2 = (unsigned)__shfl((int)a2, xl, 64);
  unsigned w3 = (unsigned)__shfl((int)a3, xl, 64);
  F.u[0] = lhi ? w2 : a0;
  F.u[1] = lhi ? w3 : a1;
  F.u[2] = lhi ? a2 : w0;
  F.u[3] = lhi ? a3 : w1;
#endif
  return F.v;
}

// ---------------------------------------------------------------------------
// Kernel 1: QKV projection via MFMA, reading W_qkv fp32 directly. V written
// TRANSPOSED via per-wave LDS tile. Extra grid row preps Wout -> Wob
// B-fragment layout for out_proj.
// ---------------------------------------------------------------------------
__global__ __launch_bounds__(256) void qkv_kernel(
    const float* __restrict__ x, const float* __restrict__ Wqkv,
    const float* __restrict__ Wout,
    __bf16* __restrict__ Q, __bf16* __restrict__ K, __bf16* __restrict__ Vt,
    __bf16* __restrict__ Wob) {
  __shared__ __bf16 T[4][64][34];       // per-wave transpose tile (+2 pad)

  if (blockIdx.y == (NROWS / 128)) {    // weight-prep row (24 blocks)
    int id = blockIdx.x * 256 + threadIdx.x;   // 0..6143
    for (int e = id; e < 512 * 64; e += 24 * 256) {
      int kf = e >> 6, col = e & 63;
      int s = kf >> 4, lh = (kf >> 3) & 1, j = kf & 7;
      int t = col >> 5, lc = col & 31;
      Wob[((size_t)((t * 32 + s) * 64 + lh * 32 + lc)) * 8 + j] = (__bf16)Wout[e];
    }
    return;
  }

  const int lane = threadIdx.x & 63;
  const int wave = threadIdx.x >> 6;
  const int l31  = lane & 31, lhi = lane >> 5;
  const int cg   = blockIdx.x;                    // 0..23 (64-col group)
  const int row0 = blockIdx.y * 128 + wave * 32;

  // A-frags: A[m=l31][k = s*16 + lhi*8 + j], fp32 -> bf16
  const float* xr = x + (size_t)(row0 + l31) * 64 + lhi * 8;
  bf16_8 af[4];
#pragma unroll
  for (int s = 0; s < 4; s++) {
    f32_4 a0 = *(const f32_4*)(xr + s * 16);
    f32_4 a1 = *(const f32_4*)(xr + s * 16 + 4);
#pragma unroll
    for (int j = 0; j < 4; j++) { af[s][j] = (__bf16)a0[j]; af[s][4 + j] = (__bf16)a1[j]; }
  }

  const int col0  = cg * 64;
  const int which = col0 >> 9;          // 0=Q 1=K 2=V
  const float wscl = (which == 0) ? QSCALE : 1.0f;

  f32_16 C0, C1;
#pragma unroll
  for (int i = 0; i < 16; i++) { C0[i] = 0.f; C1[i] = 0.f; }

  // B-frags read directly from fp32 Wqkv[k][1536]: lanes consecutive cols
#pragma unroll
  for (int s = 0; s < 4; s++) {
    bf16_8 b0, b1;
#pragma unroll
    for (int j = 0; j < 8; j++) {
      int k = s * 16 + lhi * 8 + j;
      b0[j] = (__bf16)(Wqkv[(size_t)k * QKV_COLS + col0 + l31]      * wscl);
      b1[j] = (__bf16)(Wqkv[(size_t)k * QKV_COLS + col0 + 32 + l31] * wscl);
    }
    C0 = __builtin_amdgcn_mfma_f32_32x32x16_bf16(af[s], b0, C0, 0, 0, 0);
    C1 = __builtin_amdgcn_mfma_f32_32x32x16_bf16(af[s], b1, C1, 0, 0, 0);
  }

  const int h   = (col0 >> 6) & 7;
  const int b   = row0 >> 11;
  const int n0l = row0 & 2047;

  if (which < 2) {
    __bf16* dst = (which == 0) ? Q : K;
#pragma unroll
    for (int r = 0; r < 16; r++) {
      int nl = (r & 3) + 8 * (r >> 2) + 4 * lhi;
      size_t base = (((size_t)(b * HH + h) * NN) + n0l + nl) * DD;
      dst[base + l31]      = (__bf16)C0[r];
      dst[base + 32 + l31] = (__bf16)C1[r];
    }
  } else {
    // transpose 32n x 64d -> Vt[bh][d][n]  (wave-private tile, no barrier)
    __bf16 (*Tw)[34] = T[wave];
#pragma unroll
    for (int r = 0; r < 16; r++) {
      int nl = (r & 3) + 8 * (r >> 2) + 4 * lhi;
      Tw[l31][nl]      = (__bf16)C0[r];
      Tw[32 + l31][nl] = (__bf16)C1[r];
    }
    __bf16* dst = Vt + (((size_t)(b * HH + h) * DD) + lane) * NN + n0l;
#pragma unroll
    for (int j = 0; j < 4; j++) {
      *(bf16_8*)(dst + j * 8) = *(const bf16_8*)(&Tw[lane][j * 8]);
    }
  }
}

// ---------------------------------------------------------------------------
// Kernel 2: flash attention, 8-wave blocks, 64 QUERIES PER WAVE (512/block),
// K-tile=128 double-buffered, ONE barrier/iter. In the S^T formulation the
// K/V^T LDS fragments are query-independent: each ds_read_b128 now feeds
// TWO MFMAs (subtiles a,b), halving LDS-pipe cycles per unit work vs r8.
// Grid = 256 blocks = 1 block/CU, zero tail.
// ---------------------------------------------------------------------------
#define TILE_ELEMS (128 * 72 + 64 * 136)   // 17920 bf16 = 35840 B per buffer
__global__ __launch_bounds__(512) void attn_kernel(
    const __bf16* __restrict__ Q, const __bf16* __restrict__ K,
    const __bf16* __restrict__ Vt, __bf16* __restrict__ z) {
  __shared__ __bf16 SMEM[2][TILE_ELEMS];   // 71680 B

  const int tid  = threadIdx.x;
  const int wave = tid >> 6;
  const int lane = tid & 63;
  const int l31  = lane & 31;
  const int lhi  = lane >> 5;
  const int xl   = lane ^ 32;
  const int bh   = blockIdx.x >> 2;                     // 0..63
  const int q0   = (blockIdx.x & 3) * 512 + wave * 64;  // 64 queries/wave

  // Q fragments for both subtiles (B-operand: n=query, k = s*16+lhi*8+j)
  const __bf16* Qbase = Q + ((size_t)bh * NN + q0 + l31) * DD + lhi * 8;
  bf16_8 qfa[4], qfb[4];
#pragma unroll
  for (int s = 0; s < 4; s++) {
    qfa[s] = *(const bf16_8*)(Qbase + s * 16);
    qfb[s] = *(const bf16_8*)(Qbase + (size_t)32 * DD + s * 16);
  }

  f32_16 O0a, O1a, O0b, O1b;
#pragma unroll
  for (int i = 0; i < 16; i++) { O0a[i] = 0.f; O1a[i] = 0.f; O0b[i] = 0.f; O1b[i] = 0.f; }
  float lsa = 0.f, lsb = 0.f;

  const __bf16* Kb = K  + (size_t)bh * NN * DD;
  const __bf16* Vb = Vt + (size_t)bh * DD * NN;

  // staging split across 512 threads: 2 b128 each for K and V per tile
  const int krow = tid >> 3, kcol = (tid & 7) * 8;    // K: 128 x 64
  const int vrow = tid >> 4, vcol = (tid & 15) * 8;   // V: 64 x 128
  const __bf16* kgl = Kb + (size_t)krow * 64 + kcol;
  const __bf16* vgl = Vb + (size_t)vrow * NN + vcol;
  const int koff0 = krow * 72 + kcol;
  const int voff0 = 128 * 72 + vrow * 136 + vcol;

  bf16_8 gk[2], gv[2];
#pragma unroll
  for (int i = 0; i < 2; i++) {
    gk[i] = *(const bf16_8*)(kgl + (size_t)i * 64 * 64);
    gv[i] = *(const bf16_8*)(vgl + (size_t)i * 32 * NN);
  }
  {
    __bf16* S = SMEM[0];
    *(bf16_8*)(S + koff0)            = gk[0];
    *(bf16_8*)(S + koff0 + 64 * 72)  = gk[1];
    *(bf16_8*)(S + voff0)            = gv[0];
    *(bf16_8*)(S + voff0 + 32 * 136) = gv[1];
  }
#pragma unroll
  for (int i = 0; i < 2; i++) {
    gk[i] = *(const bf16_8*)(kgl + (size_t)128 * 64 + (size_t)i * 64 * 64);
    gv[i] = *(const bf16_8*)(vgl + 128 + (size_t)i * 32 * NN);
  }
  __syncthreads();

  for (int it = 0; it < 16; it++) {
    __bf16* Ks = SMEM[it & 1];
    __bf16* Vs = SMEM[it & 1] + 128 * 72;

    // stage tile it+1 into the OTHER buffer before compute
    if (it < 15) {
      __bf16* Sn = SMEM[(it + 1) & 1];
      *(bf16_8*)(Sn + koff0)            = gk[0];
      *(bf16_8*)(Sn + koff0 + 64 * 72)  = gk[1];
      *(bf16_8*)(Sn + voff0)            = gv[0];
      *(bf16_8*)(Sn + voff0 + 32 * 136) = gv[1];
      if (it < 14) {                     // issue loads for tile it+2
        const size_t kadv = (size_t)(it + 2) * 128 * 64;
        const size_t vadv = (size_t)(it + 2) * 128;
#pragma unroll
        for (int i = 0; i < 2; i++) {
          gk[i] = *(const bf16_8*)(kgl + kadv + (size_t)i * 64 * 64);
          gv[i] = *(const bf16_8*)(vgl + vadv + (size_t)i * 32 * NN);
        }
      }
    }

#pragma unroll
    for (int hf = 0; hf < 2; hf++) {     // two 64-key halves of the tile
      // S^T = K @ Q^T for both q-subtiles; kb reads shared
      f32_16 S0a, S1a, S0b, S1b;
#pragma unroll
      for (int i = 0; i < 16; i++) { S0a[i] = 0.f; S1a[i] = 0.f; S0b[i] = 0.f; S1b[i] = 0.f; }
#pragma unroll
      for (int s = 0; s < 4; s++) {
        bf16_8 kb0 = *(const bf16_8*)(&Ks[(hf * 64 + l31) * 72 + s * 16 + lhi * 8]);
        bf16_8 kb1 = *(const bf16_8*)(&Ks[(hf * 64 + 32 + l31) * 72 + s * 16 + lhi * 8]);
        S0a = __builtin_amdgcn_mfma_f32_32x32x16_bf16(kb0, qfa[s], S0a, 0, 0, 0);
        S1a = __builtin_amdgcn_mfma_f32_32x32x16_bf16(kb1, qfa[s], S1a, 0, 0, 0);
        S0b = __builtin_amdgcn_mfma_f32_32x32x16_bf16(kb0, qfb[s], S0b, 0, 0, 0);
        S1b = __builtin_amdgcn_mfma_f32_32x32x16_bf16(kb1, qfb[s], S1b, 0, 0, 0);
      }

      // P^T = exp2(S^T) for both subtiles
      unsigned pka[16], pkb[16];
#pragma unroll
      for (int t = 0; t < 8; t++) {
        float a0 = fast_exp2(S0a[2 * t]), a1 = fast_exp2(S0a[2 * t + 1]);
        float a2 = fast_exp2(S1a[2 * t]), a3 = fast_exp2(S1a[2 * t + 1]);
        lsa += (a0 + a1) + (a2 + a3);
        pka[t]     = pack_bf16(a0, a1);
        pka[8 + t] = pack_bf16(a2, a3);
        float b0 = fast_exp2(S0b[2 * t]), b1 = fast_exp2(S0b[2 * t + 1]);
        float b2 = fast_exp2(S1b[2 * t]), b3 = fast_exp2(S1b[2 * t + 1]);
        lsb += (b0 + b1) + (b2 + b3);
        pkb[t]     = pack_bf16(b0, b1);
        pkb[8 + t] = pack_bf16(b2, b3);
      }

      // O^T += V^T @ P^T; va reads shared across subtiles
#pragma unroll
      for (int g = 0; g < 4; g++) {
        const int base = (g >> 1) * 8 + (g & 1) * 4;
        bf16_8 va0 = *(const bf16_8*)(&Vs[l31 * 136 + hf * 64 + g * 16 + lhi * 8]);
        bf16_8 va1 = *(const bf16_8*)(&Vs[(32 + l31) * 136 + hf * 64 + g * 16 + lhi * 8]);
        bf16_8 Fa = half_swap(pka[base], pka[base + 1], pka[base + 2], pka[base + 3], lhi, xl);
        O0a = __builtin_amdgcn_mfma_f32_32x32x16_bf16(va0, Fa, O0a, 0, 0, 0);
        O1a = __builtin_amdgcn_mfma_f32_32x32x16_bf16(va1, Fa, O1a, 0, 0, 0);
        bf16_8 Fb = half_swap(pkb[base], pkb[base + 1], pkb[base + 2], pkb[base + 3], lhi, xl);
        O0b = __builtin_amdgcn_mfma_f32_32x32x16_bf16(va0, Fb, O0b, 0, 0, 0);
        O1b = __builtin_amdgcn_mfma_f32_32x32x16_bf16(va1, Fb, O1b, 0, 0, 0);
      }
    }
    __syncthreads();   // single barrier: readers done, next buf staged
  }

  lsa += __shfl_xor(lsa, 32, 64);       // partner lane holds other half-keys
  lsb += __shfl_xor(lsb, 32, 64);
  const float inva = 1.f / lsa;
  const float invb = 1.f / lsb;

  // Epilogue: O^T -> per-wave LDS [q][d] (pitch 68) -> coalesced z write.
  // Two subtiles sequentially through the same wave-private region
  // (DS in-order within a wave: no barrier needed between write and read).
  const int b = bh >> 3, h = bh & 7;
  __bf16* ow = SMEM[0] + wave * (32 * 68);  // 8 x 4352 B = 34816 <= 35840
  const int qr = lane >> 1, c0 = (lane & 1) * 32;
#pragma unroll
  for (int sub = 0; sub < 2; sub++) {
    const f32_16& P0 = sub ? O0b : O0a;
    const f32_16& P1 = sub ? O1b : O1a;
    const float inv = sub ? invb : inva;
#pragma unroll
    for (int g = 0; g < 4; g++) {
      bf16_4 p0, p1;
#pragma unroll
      for (int i = 0; i < 4; i++) {
        p0[i] = (__bf16)(P0[4 * g + i] * inv);
        p1[i] = (__bf16)(P1[4 * g + i] * inv);
      }
      const int d0 = 8 * g + 4 * lhi;
      *(bf16_4*)(ow + l31 * 68 + d0)      = p0;
      *(bf16_4*)(ow + l31 * 68 + 32 + d0) = p1;
    }
    __bf16* zp = z + ((size_t)b * NN + q0 + sub * 32 + qr) * HD + h * DD + c0;
#pragma unroll
    for (int j = 0; j < 4; j++) {
      *(bf16_8*)(zp + 8 * j) = *(const bf16_8*)(ow + qr * 68 + c0 + 8 * j);
    }
  }
}

// ---------------------------------------------------------------------------
// Kernel 3: out projection, k-split x4. Block = 4 waves, one 32-row tile;
// wave w covers k in [w*128, w*128+128). Partials reduced through LDS.
// ---------------------------------------------------------------------------
__global__ __launch_bounds__(256) void out_proj_kernel(
    const __bf16* __restrict__ z, const __bf16* __restrict__ Wob,
    const float* __restrict__ bout, float* __restrict__ out) {
  __shared__ float red[3][64][33];
  const int tid  = threadIdx.x;
  const int wave = tid >> 6, lane = tid & 63;
  const int l31  = lane & 31, lhi = lane >> 5;
  const int row0 = blockIdx.x * 32;

  const __bf16* zr = z + (size_t)(row0 + l31) * HD + wave * 128 + lhi * 8;

  f32_16 C0, C1;
#pragma unroll
  for (int i = 0; i < 16; i++) { C0[i] = 0.f; C1[i] = 0.f; }

#pragma unroll
  for (int s = 0; s < 8; s++) {
    const int sa = wave * 8 + s;        // absolute k-step
    bf16_8 a  = *(const bf16_8*)(zr + s * 16);
    bf16_8 b0 = *(const bf16_8*)(Wob + ((size_t)((0 * 32 + sa) * 64 + lane)) * 8);
    bf16_8 b1 = *(const bf16_8*)(Wob + ((size_t)((1 * 32 + sa) * 64 + lane)) * 8);
    C0 = __builtin_amdgcn_mfma_f32_32x32x16_bf16(a, b0, C0, 0, 0, 0);
    C1 = __builtin_amdgcn_mfma_f32_32x32x16_bf16(a, b1, C1, 0, 0, 0);
  }

  if (wave) {
    float* rw = &red[wave - 1][lane][0];
#pragma unroll
    for (int r = 0; r < 16; r++) { rw[r] = C0[r]; rw[16 + r] = C1[r]; }
  }
  __syncthreads();
  if (wave == 0) {
    const float bi0 = bout[l31], bi1 = bout[32 + l31];
#pragma unroll
    for (int r = 0; r < 16; r++) {
      int n = row0 + (r & 3) + 8 * (r >> 2) + 4 * lhi;
      float v0 = C0[r] + red[0][lane][r]      + red[1][lane][r]      + red[2][lane][r];
      float v1 = C1[r] + red[0][lane][16 + r] + red[1][lane][16 + r] + red[2][lane][16 + r];
      out[(size_t)n * 64 + l31]      = v0 + bi0;
      out[(size_t)n * 64 + 32 + l31] = v1 + bi1;
    }
  }
}

// ---------------------------------------------------------------------------
extern "C" void kernel_launch(void* const* d_in, const int* in_sizes, int n_in,
                              void* d_out, int out_size, void* d_ws, size_t ws_size,
                              hipStream_t stream) {
  const float* x    = (const float*)d_in[0];
  const float* Wqkv = (const float*)d_in[1];
  const float* Wout = (const float*)d_in[2];
  const float* bout = (const float*)d_in[3];
  float* out = (float*)d_out;

  const size_t buf_elems = (size_t)BB * HH * NN * DD;  // 8388608
  __bf16* Qw  = (__bf16*)d_ws;
  __bf16* Kw  = Qw  + buf_elems;
  __bf16* Vtw = Kw  + buf_elems;
  __bf16* zw  = Vtw + buf_elems;
  __bf16* Wob = zw  + buf_elems;       // 32768 bf16

  qkv_kernel<<<dim3(QKV_COLS / 64, NROWS / 128 + 1), 256, 0, stream>>>(
      x, Wqkv, Wout, Qw, Kw, Vtw, Wob);
  attn_kernel<<<BH * (NN / 512), 512, 0, stream>>>(Qw, Kw, Vtw, zw);
  out_proj_kernel<<<NROWS / 32, 256, 0, stream>>>(zw, Wob, bout, out);
}

// Round 10
// 168.798 us; speedup vs baseline: 2.0322x; 1.0666x over previous
//
#include <hip/hip_runtime.h>
#include <math.h>

// Problem constants: B=8, N=2048, DIM=64, H=8
#define BB 8
#define NN 2048
#define DD 64
#define HH 8
#define BH (BB*HH)       // 64
#define HD (HH*DD)       // 512
#define NROWS (BB*NN)    // 16384
#define QKV_COLS (3*HD)  // 1536

typedef __bf16 bf16_8 __attribute__((ext_vector_type(8)));
typedef __bf16 bf16_4 __attribute__((ext_vector_type(4)));
typedef float  f32_16 __attribute__((ext_vector_type(16)));
typedef float  f32_4  __attribute__((ext_vector_type(4)));
typedef int    i32_2  __attribute__((ext_vector_type(2)));

#define QSCALE 0.180336880111f   // 0.125 * log2(e), folded into Q

__device__ __forceinline__ unsigned pack_bf16(float a, float b) {
  union { __bf16 h[2]; unsigned u; } t;
  t.h[0] = (__bf16)a; t.h[1] = (__bf16)b;
  return t.u;
}

__device__ __forceinline__ float fast_exp2(float x) {
#if __has_builtin(__builtin_amdgcn_exp2f)
  return __builtin_amdgcn_exp2f(x);      // raw v_exp_f32
#else
  return __expf(x * 0.69314718056f);
#endif
}

// half-swap across the lane-32 boundary: C-layout row-spread -> A/B-operand
// k-spread (verified rounds 3-9)
__device__ __forceinline__ bf16_8 half_swap(unsigned a0, unsigned a1,
                                            unsigned a2, unsigned a3,
                                            int lhi, int xl) {
  union { unsigned u[4]; bf16_8 v; } F;
#if __has_builtin(__builtin_amdgcn_permlane32_swap)
  i32_2 r02 = __builtin_amdgcn_permlane32_swap((int)a0, (int)a2, false, false);
  i32_2 r13 = __builtin_amdgcn_permlane32_swap((int)a1, (int)a3, false, false);
  F.u[0] = (unsigned)r02.x; F.u[2] = (unsigned)r02.y;
  F.u[1] = (unsigned)r13.x; F.u[3] = (unsigned)r13.y;
#else
  unsigned w0 = (unsigned)__shfl((int)a0, xl, 64);
  unsigned w1 = (unsigned)__shfl((int)a1, xl, 64);
  unsigned w2 = (unsigned)__shfl((int)a2, xl, 64);
  unsigned w3 = (unsigned)__shfl((int)a3, xl, 64);
  F.u[0] = lhi ? w2 : a0;
  F.u[1] = lhi ? w3 : a1;
  F.u[2] = lhi ? a2 : w0;
  F.u[3] = lhi ? a3 : w1;
#endif
  return F.v;
}

// ---------------------------------------------------------------------------
// Kernel 1: QKV projection via MFMA, reading W_qkv fp32 directly. V written
// TRANSPOSED via per-wave LDS tile. Extra grid row preps Wout -> Wob
// B-fragment layout for out_proj.
// ---------------------------------------------------------------------------
__global__ __launch_bounds__(256) void qkv_kernel(
    const float* __restrict__ x, const float* __restrict__ Wqkv,
    const float* __restrict__ Wout,
    __bf16* __restrict__ Q, __bf16* __restrict__ K, __bf16* __restrict__ Vt,
    __bf16* __restrict__ Wob) {
  __shared__ __bf16 T[4][64][34];       // per-wave transpose tile (+2 pad)

  if (blockIdx.y == (NROWS / 128)) {    // weight-prep row (24 blocks)
    int id = blockIdx.x * 256 + threadIdx.x;   // 0..6143
    for (int e = id; e < 512 * 64; e += 24 * 256) {
      int kf = e >> 6, col = e & 63;
      int s = kf >> 4, lh = (kf >> 3) & 1, j = kf & 7;
      int t = col >> 5, lc = col & 31;
      Wob[((size_t)((t * 32 + s) * 64 + lh * 32 + lc)) * 8 + j] = (__bf16)Wout[e];
    }
    return;
  }

  const int lane = threadIdx.x & 63;
  const int wave = threadIdx.x >> 6;
  const int l31  = lane & 31, lhi = lane >> 5;
  const int cg   = blockIdx.x;                    // 0..23 (64-col group)
  const int row0 = blockIdx.y * 128 + wave * 32;

  // A-frags: A[m=l31][k = s*16 + lhi*8 + j], fp32 -> bf16
  const float* xr = x + (size_t)(row0 + l31) * 64 + lhi * 8;
  bf16_8 af[4];
#pragma unroll
  for (int s = 0; s < 4; s++) {
    f32_4 a0 = *(const f32_4*)(xr + s * 16);
    f32_4 a1 = *(const f32_4*)(xr + s * 16 + 4);
#pragma unroll
    for (int j = 0; j < 4; j++) { af[s][j] = (__bf16)a0[j]; af[s][4 + j] = (__bf16)a1[j]; }
  }

  const int col0  = cg * 64;
  const int which = col0 >> 9;          // 0=Q 1=K 2=V
  const float wscl = (which == 0) ? QSCALE : 1.0f;

  f32_16 C0, C1;
#pragma unroll
  for (int i = 0; i < 16; i++) { C0[i] = 0.f; C1[i] = 0.f; }

  // B-frags read directly from fp32 Wqkv[k][1536]: lanes consecutive cols
#pragma unroll
  for (int s = 0; s < 4; s++) {
    bf16_8 b0, b1;
#pragma unroll
    for (int j = 0; j < 8; j++) {
      int k = s * 16 + lhi * 8 + j;
      b0[j] = (__bf16)(Wqkv[(size_t)k * QKV_COLS + col0 + l31]      * wscl);
      b1[j] = (__bf16)(Wqkv[(size_t)k * QKV_COLS + col0 + 32 + l31] * wscl);
    }
    C0 = __builtin_amdgcn_mfma_f32_32x32x16_bf16(af[s], b0, C0, 0, 0, 0);
    C1 = __builtin_amdgcn_mfma_f32_32x32x16_bf16(af[s], b1, C1, 0, 0, 0);
  }

  const int h   = (col0 >> 6) & 7;
  const int b   = row0 >> 11;
  const int n0l = row0 & 2047;

  if (which < 2) {
    __bf16* dst = (which == 0) ? Q : K;
#pragma unroll
    for (int r = 0; r < 16; r++) {
      int nl = (r & 3) + 8 * (r >> 2) + 4 * lhi;
      size_t base = (((size_t)(b * HH + h) * NN) + n0l + nl) * DD;
      dst[base + l31]      = (__bf16)C0[r];
      dst[base + 32 + l31] = (__bf16)C1[r];
    }
  } else {
    // transpose 32n x 64d -> Vt[bh][d][n]  (wave-private tile, no barrier)
    __bf16 (*Tw)[34] = T[wave];
#pragma unroll
    for (int r = 0; r < 16; r++) {
      int nl = (r & 3) + 8 * (r >> 2) + 4 * lhi;
      Tw[l31][nl]      = (__bf16)C0[r];
      Tw[32 + l31][nl] = (__bf16)C1[r];
    }
    __bf16* dst = Vt + (((size_t)(b * HH + h) * DD) + lane) * NN + n0l;
#pragma unroll
    for (int j = 0; j < 4; j++) {
      *(bf16_8*)(dst + j * 8) = *(const bf16_8*)(&Tw[lane][j * 8]);
    }
  }
}

// ---------------------------------------------------------------------------
// Kernel 2: flash attention, 8-wave blocks, 64 queries/wave, K-tile=128
// double-buffered, one barrier/iter. Register-liveness-shaped inner loop:
// each 32-key group computes Sa/Sb (one kb read feeds both q-subtiles),
// exps into 8+8 packed regs, then immediately consumes them in PV (one va
// read feeds both subtiles). Peak live ~190 VGPR.
// __launch_bounds__(512, 2): min 2 waves/EU -> VGPR cap 256. Round 9's
// plain bounds capped at 128 and spilled 18 MB; round 6's (512,4) capped
// at 64 and spilled 262 MB. 2 waves/SIMD, 1 block/CU is the design point.
// ---------------------------------------------------------------------------
#define TILE_ELEMS (128 * 72 + 64 * 136)   // 17920 bf16 = 35840 B per buffer
__global__ __launch_bounds__(512, 2) void attn_kernel(
    const __bf16* __restrict__ Q, const __bf16* __restrict__ K,
    const __bf16* __restrict__ Vt, __bf16* __restrict__ z) {
  __shared__ __bf16 SMEM[2][TILE_ELEMS];   // 71680 B

  const int tid  = threadIdx.x;
  const int wave = tid >> 6;
  const int lane = tid & 63;
  const int l31  = lane & 31;
  const int lhi  = lane >> 5;
  const int xl   = lane ^ 32;
  const int bh   = blockIdx.x >> 2;                     // 0..63
  const int q0   = (blockIdx.x & 3) * 512 + wave * 64;  // 64 queries/wave

  // Q fragments for both subtiles (B-operand: n=query, k = s*16+lhi*8+j)
  const __bf16* Qbase = Q + ((size_t)bh * NN + q0 + l31) * DD + lhi * 8;
  bf16_8 qfa[4], qfb[4];
#pragma unroll
  for (int s = 0; s < 4; s++) {
    qfa[s] = *(const bf16_8*)(Qbase + s * 16);
    qfb[s] = *(const bf16_8*)(Qbase + (size_t)32 * DD + s * 16);
  }

  f32_16 O0a, O1a, O0b, O1b;
#pragma unroll
  for (int i = 0; i < 16; i++) { O0a[i] = 0.f; O1a[i] = 0.f; O0b[i] = 0.f; O1b[i] = 0.f; }
  float lsa = 0.f, lsb = 0.f;

  const __bf16* Kb = K  + (size_t)bh * NN * DD;
  const __bf16* Vb = Vt + (size_t)bh * DD * NN;

  // staging split across 512 threads: 2 b128 each for K and V per tile
  const int krow = tid >> 3, kcol = (tid & 7) * 8;    // K: 128 x 64
  const int vrow = tid >> 4, vcol = (tid & 15) * 8;   // V: 64 x 128
  const __bf16* kgl = Kb + (size_t)krow * 64 + kcol;
  const __bf16* vgl = Vb + (size_t)vrow * NN + vcol;
  const int koff0 = krow * 72 + kcol;
  const int voff0 = 128 * 72 + vrow * 136 + vcol;

  bf16_8 gk[2], gv[2];
#pragma unroll
  for (int i = 0; i < 2; i++) {
    gk[i] = *(const bf16_8*)(kgl + (size_t)i * 64 * 64);
    gv[i] = *(const bf16_8*)(vgl + (size_t)i * 32 * NN);
  }
  {
    __bf16* S = SMEM[0];
    *(bf16_8*)(S + koff0)            = gk[0];
    *(bf16_8*)(S + koff0 + 64 * 72)  = gk[1];
    *(bf16_8*)(S + voff0)            = gv[0];
    *(bf16_8*)(S + voff0 + 32 * 136) = gv[1];
  }
#pragma unroll
  for (int i = 0; i < 2; i++) {
    gk[i] = *(const bf16_8*)(kgl + (size_t)128 * 64 + (size_t)i * 64 * 64);
    gv[i] = *(const bf16_8*)(vgl + 128 + (size_t)i * 32 * NN);
  }
  __syncthreads();

  for (int it = 0; it < 16; it++) {
    __bf16* Ks = SMEM[it & 1];
    __bf16* Vs = SMEM[it & 1] + 128 * 72;

    // stage tile it+1 into the OTHER buffer before compute
    if (it < 15) {
      __bf16* Sn = SMEM[(it + 1) & 1];
      *(bf16_8*)(Sn + koff0)            = gk[0];
      *(bf16_8*)(Sn + koff0 + 64 * 72)  = gk[1];
      *(bf16_8*)(Sn + voff0)            = gv[0];
      *(bf16_8*)(Sn + voff0 + 32 * 136) = gv[1];
      if (it < 14) {                     // issue loads for tile it+2
        const size_t kadv = (size_t)(it + 2) * 128 * 64;
        const size_t vadv = (size_t)(it + 2) * 128;
#pragma unroll
        for (int i = 0; i < 2; i++) {
          gk[i] = *(const bf16_8*)(kgl + kadv + (size_t)i * 64 * 64);
          gv[i] = *(const bf16_8*)(vgl + vadv + (size_t)i * 32 * NN);
        }
      }
    }

    // 4 x 32-key groups; liveness-shaped: S -> exp -> PV, then release
#pragma unroll
    for (int grp = 0; grp < 4; grp++) {
      const int kb0 = grp * 32;          // key base within tile

      f32_16 Sa, Sb;
#pragma unroll
      for (int i = 0; i < 16; i++) { Sa[i] = 0.f; Sb[i] = 0.f; }
#pragma unroll
      for (int s = 0; s < 4; s++) {
        bf16_8 kb = *(const bf16_8*)(&Ks[(kb0 + l31) * 72 + s * 16 + lhi * 8]);
        Sa = __builtin_amdgcn_mfma_f32_32x32x16_bf16(kb, qfa[s], Sa, 0, 0, 0);
        Sb = __builtin_amdgcn_mfma_f32_32x32x16_bf16(kb, qfb[s], Sb, 0, 0, 0);
      }

      unsigned pka[8], pkb[8];
#pragma unroll
      for (int t = 0; t < 8; t++) {
        float a0 = fast_exp2(Sa[2 * t]), a1 = fast_exp2(Sa[2 * t + 1]);
        lsa += a0 + a1;
        pka[t] = pack_bf16(a0, a1);
        float b0 = fast_exp2(Sb[2 * t]), b1 = fast_exp2(Sb[2 * t + 1]);
        lsb += b0 + b1;
        pkb[t] = pack_bf16(b0, b1);
      }

#pragma unroll
      for (int g = 0; g < 2; g++) {      // two 16-key chunks of this group
        const int kc = kb0 + g * 16;
        bf16_8 va0 = *(const bf16_8*)(&Vs[l31 * 136 + kc + lhi * 8]);
        bf16_8 va1 = *(const bf16_8*)(&Vs[(32 + l31) * 136 + kc + lhi * 8]);
        bf16_8 Fa = half_swap(pka[g * 4], pka[g * 4 + 1], pka[g * 4 + 2], pka[g * 4 + 3], lhi, xl);
        O0a = __builtin_amdgcn_mfma_f32_32x32x16_bf16(va0, Fa, O0a, 0, 0, 0);
        O1a = __builtin_amdgcn_mfma_f32_32x32x16_bf16(va1, Fa, O1a, 0, 0, 0);
        bf16_8 Fb = half_swap(pkb[g * 4], pkb[g * 4 + 1], pkb[g * 4 + 2], pkb[g * 4 + 3], lhi, xl);
        O0b = __builtin_amdgcn_mfma_f32_32x32x16_bf16(va0, Fb, O0b, 0, 0, 0);
        O1b = __builtin_amdgcn_mfma_f32_32x32x16_bf16(va1, Fb, O1b, 0, 0, 0);
      }
    }
    __syncthreads();   // single barrier: readers done, next buf staged
  }

  lsa += __shfl_xor(lsa, 32, 64);       // partner lane holds other half-keys
  lsb += __shfl_xor(lsb, 32, 64);
  const float inva = 1.f / lsa;
  const float invb = 1.f / lsb;

  // Epilogue: O^T -> per-wave LDS [q][d] (pitch 68) -> coalesced z write.
  const int b = bh >> 3, h = bh & 7;
  __bf16* ow = SMEM[0] + wave * (32 * 68);  // 8 x 4352 B = 34816 <= 35840
  const int qr = lane >> 1, c0 = (lane & 1) * 32;
#pragma unroll
  for (int sub = 0; sub < 2; sub++) {
    const f32_16& P0 = sub ? O0b : O0a;
    const f32_16& P1 = sub ? O1b : O1a;
    const float inv = sub ? invb : inva;
#pragma unroll
    for (int g = 0; g < 4; g++) {
      bf16_4 p0, p1;
#pragma unroll
      for (int i = 0; i < 4; i++) {
        p0[i] = (__bf16)(P0[4 * g + i] * inv);
        p1[i] = (__bf16)(P1[4 * g + i] * inv);
      }
      const int d0 = 8 * g + 4 * lhi;
      *(bf16_4*)(ow + l31 * 68 + d0)      = p0;
      *(bf16_4*)(ow + l31 * 68 + 32 + d0) = p1;
    }
    __bf16* zp = z + ((size_t)b * NN + q0 + sub * 32 + qr) * HD + h * DD + c0;
#pragma unroll
    for (int j = 0; j < 4; j++) {
      *(bf16_8*)(zp + 8 * j) = *(const bf16_8*)(ow + qr * 68 + c0 + 8 * j);
    }
  }
}

// ---------------------------------------------------------------------------
// Kernel 3: out projection, k-split x4. Block = 4 waves, one 32-row tile;
// wave w covers k in [w*128, w*128+128). Partials reduced through LDS.
// ---------------------------------------------------------------------------
__global__ __launch_bounds__(256) void out_proj_kernel(
    const __bf16* __restrict__ z, const __bf16* __restrict__ Wob,
    const float* __restrict__ bout, float* __restrict__ out) {
  __shared__ float red[3][64][33];
  const int tid  = threadIdx.x;
  const int wave = tid >> 6, lane = tid & 63;
  const int l31  = lane & 31, lhi = lane >> 5;
  const int row0 = blockIdx.x * 32;

  const __bf16* zr = z + (size_t)(row0 + l31) * HD + wave * 128 + lhi * 8;

  f32_16 C0, C1;
#pragma unroll
  for (int i = 0; i < 16; i++) { C0[i] = 0.f; C1[i] = 0.f; }

#pragma unroll
  for (int s = 0; s < 8; s++) {
    const int sa = wave * 8 + s;        // absolute k-step
    bf16_8 a  = *(const bf16_8*)(zr + s * 16);
    bf16_8 b0 = *(const bf16_8*)(Wob + ((size_t)((0 * 32 + sa) * 64 + lane)) * 8);
    bf16_8 b1 = *(const bf16_8*)(Wob + ((size_t)((1 * 32 + sa) * 64 + lane)) * 8);
    C0 = __builtin_amdgcn_mfma_f32_32x32x16_bf16(a, b0, C0, 0, 0, 0);
    C1 = __builtin_amdgcn_mfma_f32_32x32x16_bf16(a, b1, C1, 0, 0, 0);
  }

  if (wave) {
    float* rw = &red[wave - 1][lane][0];
#pragma unroll
    for (int r = 0; r < 16; r++) { rw[r] = C0[r]; rw[16 + r] = C1[r]; }
  }
  __syncthreads();
  if (wave == 0) {
    const float bi0 = bout[l31], bi1 = bout[32 + l31];
#pragma unroll
    for (int r = 0; r < 16; r++) {
      int n = row0 + (r & 3) + 8 * (r >> 2) + 4 * lhi;
      float v0 = C0[r] + red[0][lane][r]      + red[1][lane][r]      + red[2][lane][r];
      float v1 = C1[r] + red[0][lane][16 + r] + red[1][lane][16 + r] + red[2][lane][16 + r];
      out[(size_t)n * 64 + l31]      = v0 + bi0;
      out[(size_t)n * 64 + 32 + l31] = v1 + bi1;
    }
  }
}

// ---------------------------------------------------------------------------
extern "C" void kernel_launch(void* const* d_in, const int* in_sizes, int n_in,
                              void* d_out, int out_size, void* d_ws, size_t ws_size,
                              hipStream_t stream) {
  const float* x    = (const float*)d_in[0];
  const float* Wqkv = (const float*)d_in[1];
  const float* Wout = (const float*)d_in[2];
  const float* bout = (const float*)d_in[3];
  float* out = (float*)d_out;

  const size_t buf_elems = (size_t)BB * HH * NN * DD;  // 8388608
  __bf16* Qw  = (__bf16*)d_ws;
  __bf16* Kw  = Qw  + buf_elems;
  __bf16* Vtw = Kw  + buf_elems;
  __bf16* zw  = Vtw + buf_elems;
  __bf16* Wob = zw  + buf_elems;       // 32768 bf16

  qkv_kernel<<<dim3(QKV_COLS / 64, NROWS / 128 + 1), 256, 0, stream>>>(
      x, Wqkv, Wout, Qw, Kw, Vtw, Wob);
  attn_kernel<<<BH * (NN / 512), 512, 0, stream>>>(Qw, Kw, Vtw, zw);
  out_proj_kernel<<<NROWS / 32, 256, 0, stream>>>(zw, Wob, bout, out);
}